// Round 2
// baseline (933.942 us; speedup 1.0000x reference)
//
#include <hip/hip_runtime.h>

// Problem constants
static constexpr int L_ = 3, B_ = 8, C_ = 64, N_ = 1024;
static constexpr int PLANE = C_ * N_;       // 65536
static constexpr int SZ    = L_ * B_ * PLANE; // 1572864 (srcs size, also per-stack-slot count)
static constexpr int BPL   = B_ * PLANE;    // 524288

#define DI __device__ __forceinline__

DI float wred_max(float v) {
#pragma unroll
  for (int m = 1; m < 64; m <<= 1) v = fmaxf(v, __shfl_xor(v, m, 64));
  return v;
}
DI float wred_sum(float v) {
#pragma unroll
  for (int m = 1; m < 64; m <<= 1) v += __shfl_xor(v, m, 64);
  return v;
}

// ---------------------------------------------------------------------------
// conv0: 3x3 stride-2 pad-1, Cin=128 -> Cout=64, 64x64 -> 32x32.
// grid (128, 2): x = b*16 + 2-row slab, y selects (src,tgt).
// ---------------------------------------------------------------------------
__global__ __launch_bounds__(256) void conv0_kernel(
    const float* __restrict__ in_s, const float* __restrict__ w_s, const float* __restrict__ b_s,
    float* __restrict__ outA_s, float* __restrict__ outB_s,
    const float* __restrict__ in_t, const float* __restrict__ w_t, const float* __restrict__ b_t,
    float* __restrict__ outA_t, float* __restrict__ outB_t)
{
  const int tsel = blockIdx.y;
  const float* in   = tsel ? in_t  : in_s;
  const float* w    = tsel ? w_t   : w_s;
  const float* bias = tsel ? b_t   : b_s;
  float* outA = tsel ? outA_t : outA_s;
  float* outB = tsel ? outB_t : outB_s;

  const int bx = blockIdx.x;
  const int b  = bx >> 4;
  const int y0 = (bx & 15) * 2;
  const int t  = threadIdx.x;
  const int x  = t & 31;
  const int cg = t >> 5;            // 0..7 -> co = cg*8..+7

  __shared__ float wch[8][9][64];   // [ci_chunk][k][co]
  __shared__ float inch[8][5][64];  // [ci_chunk][row][ix]

  float acc[2][8];
#pragma unroll
  for (int yy = 0; yy < 2; ++yy)
#pragma unroll
    for (int o = 0; o < 8; ++o) acc[yy][o] = 0.f;

  for (int ci0 = 0; ci0 < 128; ci0 += 8) {
    __syncthreads();
#pragma unroll
    for (int r = 0; r < 18; ++r) {            // 4608 weights
      int e = t + 256 * r;
      int cc = e / 576;
      int rem = e - cc * 576;
      int k9 = rem >> 6;
      int co = rem & 63;
      wch[cc][k9][co] = w[(co * 128 + ci0 + cc) * 9 + k9];
    }
#pragma unroll
    for (int r = 0; r < 10; ++r) {            // 2560 inputs
      int e = t + 256 * r;
      int cc = e / 320;
      int rem = e - cc * 320;
      int ry = rem >> 6;
      int ix = rem & 63;
      int iy = 2 * y0 - 1 + ry;
      float v = 0.f;
      if (iy >= 0 && iy < 64) v = in[((b * 128 + ci0 + cc) * 64 + iy) * 64 + ix];
      inch[cc][ry][ix] = v;
    }
    __syncthreads();
#pragma unroll
    for (int cc = 0; cc < 8; ++cc) {
#pragma unroll
      for (int ky = 0; ky < 3; ++ky) {
#pragma unroll
        for (int kx = 0; kx < 3; ++kx) {
          const int ix = 2 * x + kx - 1;      // [-1, 63]
          float i0 = 0.f, i1 = 0.f;
          if (ix >= 0) {
            i0 = inch[cc][ky][ix];
            i1 = inch[cc][ky + 2][ix];
          }
          const int k9 = ky * 3 + kx;
          const float4 wa = *reinterpret_cast<const float4*>(&wch[cc][k9][cg * 8]);
          const float4 wb = *reinterpret_cast<const float4*>(&wch[cc][k9][cg * 8 + 4]);
          const float wv[8] = {wa.x, wa.y, wa.z, wa.w, wb.x, wb.y, wb.z, wb.w};
#pragma unroll
          for (int o = 0; o < 8; ++o) {
            acc[0][o] = fmaf(i0, wv[o], acc[0][o]);
            acc[1][o] = fmaf(i1, wv[o], acc[1][o]);
          }
        }
      }
    }
  }
#pragma unroll
  for (int o = 0; o < 8; ++o) {
    const int co = cg * 8 + o;
    const float bv = bias[co];
#pragma unroll
    for (int yy = 0; yy < 2; ++yy) {
      const int idx = (b * 64 + co) * 1024 + (y0 + yy) * 32 + x;
      const float val = acc[yy][o] + bv;
      outA[idx] = val;
      if (outB) outB[idx] = val;
    }
  }
}

// ---------------------------------------------------------------------------
// Generic out[g][64][1024] = W[g/wdiv][64][K] @ X[g][K][1024] + bias
// grid (G, 16): 64-col n-tiles. Optional scalar dual-write to out2 (unaligned ok).
// ---------------------------------------------------------------------------
__global__ __launch_bounds__(256) void gemm64_kernel(
    const float* __restrict__ W, int wstride, int wdiv,
    const float* __restrict__ X, int xstride,
    float* __restrict__ out, int ostride,
    float* __restrict__ out2, int o2stride,
    const float* __restrict__ bias, int bstride,
    int K)
{
  const int g  = blockIdx.x;
  const int n0 = blockIdx.y * 64;
  const float* Wg = W + (size_t)(g / wdiv) * wstride;
  const float* Xg = X + (size_t)g * xstride;
  const int t = threadIdx.x;
  __shared__ float Xs[32][64];
  __shared__ float Ws[32][64];
  const int tn = t & 15, cgp = t >> 4;
  const int n4 = tn * 4, co4 = cgp * 4;
  float acc[4][4] = {};

  for (int k0 = 0; k0 < K; k0 += 32) {
    {
      const int kk = t >> 4;
      const int nn = (t & 15) * 4;
      *reinterpret_cast<float4*>(&Xs[kk][nn]) =
          *reinterpret_cast<const float4*>(Xg + (size_t)(k0 + kk) * N_ + n0 + nn);
      *reinterpret_cast<float4*>(&Xs[kk + 16][nn]) =
          *reinterpret_cast<const float4*>(Xg + (size_t)(k0 + kk + 16) * N_ + n0 + nn);
    }
    {
      const int co = t & 63, q4 = t >> 6;
      const float* wp = Wg + (size_t)co * K + k0 + q4 * 8;
      const float4 a = *reinterpret_cast<const float4*>(wp);
      const float4 c = *reinterpret_cast<const float4*>(wp + 4);
      const int kb = q4 * 8;
      Ws[kb + 0][co] = a.x; Ws[kb + 1][co] = a.y; Ws[kb + 2][co] = a.z; Ws[kb + 3][co] = a.w;
      Ws[kb + 4][co] = c.x; Ws[kb + 5][co] = c.y; Ws[kb + 6][co] = c.z; Ws[kb + 7][co] = c.w;
    }
    __syncthreads();
#pragma unroll
    for (int kk = 0; kk < 32; ++kk) {
      const float4 xv = *reinterpret_cast<const float4*>(&Xs[kk][n4]);
      const float4 wv = *reinterpret_cast<const float4*>(&Ws[kk][co4]);
      const float xa[4] = {xv.x, xv.y, xv.z, xv.w};
      const float wa[4] = {wv.x, wv.y, wv.z, wv.w};
#pragma unroll
      for (int a = 0; a < 4; ++a)
#pragma unroll
        for (int b2 = 0; b2 < 4; ++b2)
          acc[a][b2] = fmaf(wa[a], xa[b2], acc[a][b2]);
    }
    __syncthreads();
  }

  float bv[4] = {0.f, 0.f, 0.f, 0.f};
  if (bias) {
    const float* bg = bias + (size_t)(g / wdiv) * bstride;
    bv[0] = bg[co4]; bv[1] = bg[co4 + 1]; bv[2] = bg[co4 + 2]; bv[3] = bg[co4 + 3];
  }
#pragma unroll
  for (int ii = 0; ii < 4; ++ii) {
    float4 o4;
    o4.x = acc[ii][0] + bv[ii]; o4.y = acc[ii][1] + bv[ii];
    o4.z = acc[ii][2] + bv[ii]; o4.w = acc[ii][3] + bv[ii];
    const int idx = (co4 + ii) * N_ + n0 + n4;
    *reinterpret_cast<float4*>(out + (size_t)g * ostride + idx) = o4;
    if (out2) {
      float* o2 = out2 + (size_t)g * o2stride + idx;
      o2[0] = o4.x; o2[1] = o4.y; o2[2] = o4.z; o2[3] = o4.w;
    }
  }
}

// ---------------------------------------------------------------------------
// e_cam[i,j,b][c][d] = sum_n T[i,b,c,n] * S[j,b,d,n];  also atomic raw-sum.
// grid 72 = (i,j,b)
// ---------------------------------------------------------------------------
__global__ __launch_bounds__(256) void ecam_kernel(
    const float* __restrict__ T, const float* __restrict__ S,
    float* __restrict__ ecam, float* __restrict__ esum_cam)
{
  const int bx = blockIdx.x;
  const int b = bx & 7;
  const int j = (bx >> 3) % 3;
  const int i = bx / 24;
  const float* Tg = T + (size_t)(i * 8 + b) * PLANE;
  const float* Sg = S + (size_t)(j * 8 + b) * PLANE;
  const int t = threadIdx.x;
  __shared__ float Ts[64 * 68];
  __shared__ float Ss[64 * 68];
  __shared__ float rs[4];
  float acc[4][4] = {};
  const int c0 = (t & 15) * 4, d0 = (t >> 4) * 4;

  for (int nb = 0; nb < 1024; nb += 64) {
    __syncthreads();
    {
      const int nn = t & 63, rb = t >> 6;
#pragma unroll
      for (int r = 0; r < 16; ++r) {
        const int row = rb * 16 + r;
        Ts[nn * 68 + row] = Tg[row * N_ + nb + nn];
        Ss[nn * 68 + row] = Sg[row * N_ + nb + nn];
      }
    }
    __syncthreads();
#pragma unroll 8
    for (int nn = 0; nn < 64; ++nn) {
      const float4 tv = *reinterpret_cast<const float4*>(&Ts[nn * 68 + c0]);
      const float4 sv = *reinterpret_cast<const float4*>(&Ss[nn * 68 + d0]);
      const float ta[4] = {tv.x, tv.y, tv.z, tv.w};
      const float sa[4] = {sv.x, sv.y, sv.z, sv.w};
#pragma unroll
      for (int ci = 0; ci < 4; ++ci)
#pragma unroll
        for (int di = 0; di < 4; ++di)
          acc[ci][di] = fmaf(ta[ci], sa[di], acc[ci][di]);
    }
  }
  float s = 0.f;
#pragma unroll
  for (int ci = 0; ci < 4; ++ci)
#pragma unroll
    for (int di = 0; di < 4; ++di) s += acc[ci][di];
  s = wred_sum(s);
  if ((t & 63) == 0) rs[t >> 6] = s;
  __syncthreads();
  if (t == 0) atomicAdd(esum_cam + i * 3 + j, rs[0] + rs[1] + rs[2] + rs[3]);

  float* eo = ecam + (size_t)((i * 3 + j) * 8 + b) * 4096;
#pragma unroll
  for (int ci = 0; ci < 4; ++ci) {
    float4 o4; o4.x = acc[ci][0]; o4.y = acc[ci][1]; o4.z = acc[ci][2]; o4.w = acc[ci][3];
    *reinterpret_cast<float4*>(eo + (c0 + ci) * 64 + d0) = o4;
  }
}

// ---------------------------------------------------------------------------
// attn_cam[i,b][c][d] = sum_j softmax_d(e_cam[i,j,b,c,:])[d]     grid 24
// ---------------------------------------------------------------------------
__global__ __launch_bounds__(256) void acam_kernel(
    const float* __restrict__ ecam, float* __restrict__ acam)
{
  const int bx = blockIdx.x;
  const int b = bx & 7, i = bx >> 3;
  const int t = threadIdx.x;
  const int c = t >> 2, seg = t & 3;
  float acc[16] = {};
#pragma unroll
  for (int j = 0; j < 3; ++j) {
    const float* e = ecam + (size_t)((i * 3 + j) * 8 + b) * 4096 + c * 64 + seg * 16;
    float ev[16];
#pragma unroll
    for (int r = 0; r < 4; ++r) {
      const float4 v4 = *reinterpret_cast<const float4*>(e + r * 4);
      ev[4 * r] = v4.x; ev[4 * r + 1] = v4.y; ev[4 * r + 2] = v4.z; ev[4 * r + 3] = v4.w;
    }
    float mx = ev[0];
#pragma unroll
    for (int r = 1; r < 16; ++r) mx = fmaxf(mx, ev[r]);
    mx = fmaxf(mx, __shfl_xor(mx, 1, 4));
    mx = fmaxf(mx, __shfl_xor(mx, 2, 4));
    float pv[16], ss = 0.f;
#pragma unroll
    for (int r = 0; r < 16; ++r) { pv[r] = __expf(ev[r] - mx); ss += pv[r]; }
    ss += __shfl_xor(ss, 1, 4);
    ss += __shfl_xor(ss, 2, 4);
    const float rc = 1.f / ss;
#pragma unroll
    for (int r = 0; r < 16; ++r) acc[r] += pv[r] * rc;
  }
  float* ao = acam + (size_t)(i * 8 + b) * 4096 + c * 64 + seg * 16;
#pragma unroll
  for (int r = 0; r < 4; ++r) {
    float4 o4; o4.x = acc[4 * r]; o4.y = acc[4 * r + 1]; o4.z = acc[4 * r + 2]; o4.w = acc[4 * r + 3];
    *reinterpret_cast<float4*>(ao + r * 4) = o4;
  }
}

// ---------------------------------------------------------------------------
// PAM: per (i,b,16-query tile): logits over all (j,m) with per-thread 4 m cols,
// softmax per j (wave+block reduce), Sum_j probs kept in regs, PV via LDS pT.
// grid 1536
// ---------------------------------------------------------------------------
__global__ __launch_bounds__(256, 2) void pam_kernel(
    const float* __restrict__ q, const float* __restrict__ k, const float* __restrict__ v,
    const float* __restrict__ ocam, float* __restrict__ tgts, float* __restrict__ esum_pam)
{
  const int bx = blockIdx.x;
  const int qt = bx & 63;
  const int b  = (bx >> 6) & 7;
  const int i  = bx >> 9;
  const int n0 = qt * 16;
  const int t = threadIdx.x;
  const int lane = t & 63;
  const int wv = t >> 6;

  __shared__ float pT[512][16];   // 32 KB, swizzled columns
  __shared__ float ub[2304];      // union: {qs[1024], redmx[64], redse[64], redes[4]} | vsT[32*72]
  float* qs    = ub;
  float* redmx = ub + 1024;
  float* redse = ub + 1088;
  float* redes = ub + 1152;

  const size_t ibo = (size_t)(i * 8 + b) * PLANE;
  const float* qg = q + ibo;
  for (int e = t; e < 1024; e += 256) {
    const int c = e >> 4, nn = e & 15;
    qs[c * 16 + nn] = qg[c * N_ + n0 + nn];
  }

  float pacc[4][16] = {};
  __syncthreads();

  for (int j = 0; j < 3; ++j) {
    const float* kg = k + (size_t)(j * 8 + b) * PLANE + 4 * t;
    float l[4][16] = {};
#pragma unroll 2
    for (int c = 0; c < 64; ++c) {
      const float4 kv = *reinterpret_cast<const float4*>(kg + c * N_);
      const float km[4] = {kv.x, kv.y, kv.z, kv.w};
      float qv[16];
      *reinterpret_cast<float4*>(&qv[0])  = *reinterpret_cast<const float4*>(&qs[c * 16 + 0]);
      *reinterpret_cast<float4*>(&qv[4])  = *reinterpret_cast<const float4*>(&qs[c * 16 + 4]);
      *reinterpret_cast<float4*>(&qv[8])  = *reinterpret_cast<const float4*>(&qs[c * 16 + 8]);
      *reinterpret_cast<float4*>(&qv[12]) = *reinterpret_cast<const float4*>(&qs[c * 16 + 12]);
#pragma unroll
      for (int mi = 0; mi < 4; ++mi)
#pragma unroll
        for (int ni = 0; ni < 16; ++ni)
          l[mi][ni] = fmaf(km[mi], qv[ni], l[mi][ni]);
    }
    // row maxes + raw logit sum
    float lm[16];
#pragma unroll
    for (int ni = 0; ni < 16; ++ni)
      lm[ni] = fmaxf(fmaxf(l[0][ni], l[1][ni]), fmaxf(l[2][ni], l[3][ni]));
#pragma unroll
    for (int ni = 0; ni < 16; ++ni) lm[ni] = wred_max(lm[ni]);
    float es = 0.f;
#pragma unroll
    for (int mi = 0; mi < 4; ++mi)
#pragma unroll
      for (int ni = 0; ni < 16; ++ni) es += l[mi][ni];
    es = wred_sum(es);
    if (lane == 0) {
#pragma unroll
      for (int ni = 0; ni < 16; ++ni) redmx[wv * 16 + ni] = lm[ni];
      redes[wv] = es;
    }
    __syncthreads();
    float mx[16];
#pragma unroll
    for (int ni = 0; ni < 16; ++ni)
      mx[ni] = fmaxf(fmaxf(redmx[ni], redmx[16 + ni]), fmaxf(redmx[32 + ni], redmx[48 + ni]));
    if (t == 0) atomicAdd(esum_pam + i * 3 + j, redes[0] + redes[1] + redes[2] + redes[3]);
    // exp + sums
    float se[16];
#pragma unroll
    for (int ni = 0; ni < 16; ++ni) se[ni] = 0.f;
#pragma unroll
    for (int mi = 0; mi < 4; ++mi)
#pragma unroll
      for (int ni = 0; ni < 16; ++ni) {
        l[mi][ni] = __expf(l[mi][ni] - mx[ni]);
        se[ni] += l[mi][ni];
      }
#pragma unroll
    for (int ni = 0; ni < 16; ++ni) se[ni] = wred_sum(se[ni]);
    if (lane == 0) {
#pragma unroll
      for (int ni = 0; ni < 16; ++ni) redse[wv * 16 + ni] = se[ni];
    }
    __syncthreads();
    float rse[16];
#pragma unroll
    for (int ni = 0; ni < 16; ++ni)
      rse[ni] = 1.f / (redse[ni] + redse[16 + ni] + redse[32 + ni] + redse[48 + ni]);
#pragma unroll
    for (int mi = 0; mi < 4; ++mi)
#pragma unroll
      for (int ni = 0; ni < 16; ++ni)
        pacc[mi][ni] += l[mi][ni] * rse[ni];
    __syncthreads();
  }

  // ---- PV: out[c][n] = sum_m v[c][m] * pacc[n][m], two 512-m halves ----
  const float* vg = v + ibo;
  float oacc[4][4] = {};
  const int mq  = lane >> 4;
  const int sub = lane & 15;
  const int c0  = wv * 16 + (sub & 3) * 4;
  const int nb  = (sub >> 2) * 4;
  float* vsT = ub;  // [32][72]

  for (int half = 0; half < 2; ++half) {
    __syncthreads();
    if ((t >> 7) == half) {
      const int tt = t & 127;
#pragma unroll
      for (int mi = 0; mi < 4; ++mi) {
        const int row = tt * 4 + mi;               // row within half
        const int sw = ((row >> 2) & 3) << 2;
#pragma unroll
        for (int gcol = 0; gcol < 16; gcol += 4) {
          float4 w4;
          w4.x = pacc[mi][gcol]; w4.y = pacc[mi][gcol + 1];
          w4.z = pacc[mi][gcol + 2]; w4.w = pacc[mi][gcol + 3];
          *reinterpret_cast<float4*>(&pT[row][gcol ^ sw]) = w4;
        }
      }
    }
    __syncthreads();
    for (int mc = 0; mc < 512; mc += 32) {
      const int mbase = half * 512 + mc;
      {
        const int nn = t & 31, rb = t >> 5;
#pragma unroll
        for (int r = 0; r < 8; ++r) {
          const int c = rb * 8 + r;
          vsT[nn * 72 + c] = vg[c * N_ + mbase + nn];
        }
      }
      __syncthreads();
#pragma unroll
      for (int mi = 0; mi < 8; ++mi) {
        const int mm = mi * 4 + mq;
        const int row = mc + mm;
        const int sw = ((row >> 2) & 3) << 2;
        const float4 pv = *reinterpret_cast<const float4*>(&pT[row][nb ^ sw]);
        const float4 vvv = *reinterpret_cast<const float4*>(&vsT[mm * 72 + c0]);
        const float pa[4] = {pv.x, pv.y, pv.z, pv.w};
        const float va[4] = {vvv.x, vvv.y, vvv.z, vvv.w};
#pragma unroll
        for (int ci = 0; ci < 4; ++ci)
#pragma unroll
          for (int ni = 0; ni < 4; ++ni)
            oacc[ci][ni] = fmaf(va[ci], pa[ni], oacc[ci][ni]);
      }
      __syncthreads();
    }
  }
  // reduce m-quarters (lanes mq 0..3 within wave)
#pragma unroll
  for (int ci = 0; ci < 4; ++ci)
#pragma unroll
    for (int ni = 0; ni < 4; ++ni) {
      oacc[ci][ni] += __shfl_xor(oacc[ci][ni], 16, 64);
      oacc[ci][ni] += __shfl_xor(oacc[ci][ni], 32, 64);
    }
  if (mq == 0) {
    const float* og = ocam + ibo;
    float* outg = tgts + (size_t)(2 * i * 8 + b) * PLANE;
#pragma unroll
    for (int ci = 0; ci < 4; ++ci)
#pragma unroll
      for (int ni = 0; ni < 4; ++ni) {
        const int idx = (c0 + ci) * N_ + n0 + nb + ni;
        outg[idx] = 0.5f * (oacc[ci][ni] + og[idx]);
      }
  }
}

// ---------------------------------------------------------------------------
// alpha[i][j] = 0.5*(softmax_j(mean e_pam) + softmax_j(mean e_cam))
// ---------------------------------------------------------------------------
__global__ void alpha_kernel(const float* __restrict__ esum, float* __restrict__ alpha)
{
  const int t = threadIdx.x;
  if (t >= 9) return;
  const int i = t / 3, j = t % 3;
  float p[3], c[3];
#pragma unroll
  for (int jj = 0; jj < 3; ++jj) {
    p[jj] = esum[i * 3 + jj] * (1.0f / 8388608.0f);
    c[jj] = esum[9 + i * 3 + jj] * (1.0f / 32768.0f);
  }
  const float mp = fmaxf(p[0], fmaxf(p[1], p[2]));
  const float mc = fmaxf(c[0], fmaxf(c[1], c[2]));
  float sp = 0.f, sc = 0.f;
#pragma unroll
  for (int jj = 0; jj < 3; ++jj) { sp += __expf(p[jj] - mp); sc += __expf(c[jj] - mc); }
  alpha[t] = 0.5f * (__expf(p[j] - mp) / sp + __expf(c[j] - mc) / sc);
}

// ---------------------------------------------------------------------------
extern "C" void kernel_launch(void* const* d_in, const int* in_sizes, int n_in,
                              void* d_out, int out_size, void* d_ws, size_t ws_size,
                              hipStream_t stream)
{
  const float* src0 = (const float*)d_in[0];
  const float* src1 = (const float*)d_in[1];
  const float* src2 = (const float*)d_in[2];
  const float* tgt0 = (const float*)d_in[3];
  const float* tgt1 = (const float*)d_in[4];
  const float* tgt2 = (const float*)d_in[5];
  const float* fs0_w = (const float*)d_in[6];  const float* fs0_b = (const float*)d_in[7];
  const float* fs1_w = (const float*)d_in[8];  const float* fs1_b = (const float*)d_in[9];
  const float* fs2_w = (const float*)d_in[10]; const float* fs2_b = (const float*)d_in[11];
  const float* ft0_w = (const float*)d_in[12]; const float* ft0_b = (const float*)d_in[13];
  const float* ft1_w = (const float*)d_in[14]; const float* ft1_b = (const float*)d_in[15];
  const float* ft2_w = (const float*)d_in[16]; const float* ft2_b = (const float*)d_in[17];
  const float* pq_w = (const float*)d_in[18];  const float* pq_b = (const float*)d_in[19];
  const float* pk_w = (const float*)d_in[20];  const float* pk_b = (const float*)d_in[21];
  const float* pv_w = (const float*)d_in[22];  const float* pv_b = (const float*)d_in[23];
  const float* cv_w = (const float*)d_in[24];  const float* cv_b = (const float*)d_in[25];

  float* out = (float*)d_out;
  float* S     = out;                 // srcs region doubles as S storage
  float* alpha = out + SZ;            // 9 floats
  float* tgts  = out + SZ + 9;        // [2L][B][PLANE]

  float* ws   = (float*)d_ws;
  float* T    = ws;
  float* qb   = ws + (size_t)SZ;
  float* kb   = ws + (size_t)2 * SZ;
  float* vb   = ws + (size_t)3 * SZ;
  float* vcb  = ws + (size_t)4 * SZ;
  float* ocam = ws + (size_t)5 * SZ;
  float* ecam = ws + (size_t)6 * SZ;                 // 294912
  float* acam = ws + (size_t)6 * SZ + 294912;        // 98304
  float* esum = ws + (size_t)6 * SZ + 393216;        // 18 (pam 9, cam 9)

  hipMemsetAsync(esum, 0, 18 * sizeof(float), stream);

  // Fit convs (S goes straight into d_out; T dual-written into tgts odd slots)
  conv0_kernel<<<dim3(128, 2), 256, 0, stream>>>(
      src0, fs0_w, fs0_b, S, nullptr,
      tgt0, ft0_w, ft0_b, T, tgts + (size_t)1 * BPL);
  gemm64_kernel<<<dim3(8, 16), 256, 0, stream>>>(fs1_w, 0, 1, src1, 256 * N_, S + BPL, PLANE,
                                                 nullptr, 0, fs1_b, 0, 256);
  gemm64_kernel<<<dim3(8, 16), 256, 0, stream>>>(fs2_w, 0, 1, src2, 512 * N_, S + 2 * BPL, PLANE,
                                                 nullptr, 0, fs2_b, 0, 512);
  gemm64_kernel<<<dim3(8, 16), 256, 0, stream>>>(ft1_w, 0, 1, tgt1, 256 * N_, T + BPL, PLANE,
                                                 tgts + (size_t)3 * BPL, PLANE, ft1_b, 0, 256);
  gemm64_kernel<<<dim3(8, 16), 256, 0, stream>>>(ft2_w, 0, 1, tgt2, 512 * N_, T + 2 * BPL, PLANE,
                                                 tgts + (size_t)5 * BPL, PLANE, ft2_b, 0, 512);

  // Projections q,k,v,vc
  gemm64_kernel<<<dim3(24, 16), 256, 0, stream>>>(pq_w, 4096, 8, T, PLANE, qb, PLANE,
                                                  nullptr, 0, pq_b, 64, 64);
  gemm64_kernel<<<dim3(24, 16), 256, 0, stream>>>(pk_w, 4096, 8, S, PLANE, kb, PLANE,
                                                  nullptr, 0, pk_b, 64, 64);
  gemm64_kernel<<<dim3(24, 16), 256, 0, stream>>>(pv_w, 4096, 8, T, PLANE, vb, PLANE,
                                                  nullptr, 0, pv_b, 64, 64);
  gemm64_kernel<<<dim3(24, 16), 256, 0, stream>>>(cv_w, 4096, 8, T, PLANE, vcb, PLANE,
                                                  nullptr, 0, cv_b, 64, 64);

  // CAM
  ecam_kernel<<<72, 256, 0, stream>>>(T, S, ecam, esum + 9);
  acam_kernel<<<24, 256, 0, stream>>>(ecam, acam);
  gemm64_kernel<<<dim3(24, 16), 256, 0, stream>>>(acam, 4096, 1, vcb, PLANE, ocam, PLANE,
                                                  nullptr, 0, nullptr, 0, 64);

  // PAM + fuse (writes tgts even slots = 0.5*(out_pam + out_cam))
  pam_kernel<<<1536, 256, 0, stream>>>(qb, kb, vb, ocam, tgts, esum);

  alpha_kernel<<<1, 64, 0, stream>>>(esum, alpha);
}

// Round 3
// 915.772 us; speedup vs baseline: 1.0198x; 1.0198x over previous
//
#include <hip/hip_runtime.h>

// Problem constants
static constexpr int L_ = 3, B_ = 8, C_ = 64, N_ = 1024;
static constexpr int PLANE = C_ * N_;       // 65536
static constexpr int SZ    = L_ * B_ * PLANE; // 1572864 (srcs size, also per-stack-slot count)
static constexpr int BPL   = B_ * PLANE;    // 524288

#define DI __device__ __forceinline__

DI float wred_max(float v) {
#pragma unroll
  for (int m = 1; m < 64; m <<= 1) v = fmaxf(v, __shfl_xor(v, m, 64));
  return v;
}
DI float wred_sum(float v) {
#pragma unroll
  for (int m = 1; m < 64; m <<= 1) v += __shfl_xor(v, m, 64);
  return v;
}

// ---------------------------------------------------------------------------
// Weight transpose: w[co][ci][k9] -> wT[ci][k9][co]  (64 x 128 x 9 each)
// grid (288, 2)
// ---------------------------------------------------------------------------
__global__ __launch_bounds__(256) void wtrans_kernel(
    const float* __restrict__ w_s, const float* __restrict__ w_t,
    float* __restrict__ wT_s, float* __restrict__ wT_t)
{
  const float* w = blockIdx.y ? w_t : w_s;
  float* wT = blockIdx.y ? wT_t : wT_s;
  const int e = blockIdx.x * 256 + threadIdx.x;   // 0..73727
  const int co = e & 63;
  const int q = e >> 6;
  const int k9 = q % 9;
  const int ci = q / 9;
  wT[e] = w[(co * 128 + ci) * 9 + k9];
}

// ---------------------------------------------------------------------------
// conv0: 3x3 stride-2 pad-1, Cin=128 -> Cout=64, 64x64 -> 32x32.
// grid (128, 2): x = b*16 + 2-row slab, y selects (src,tgt).
// Weights come pre-transposed as wT[ci][k9][co] so staging is a flat copy.
// ---------------------------------------------------------------------------
__global__ __launch_bounds__(256) void conv0_kernel(
    const float* __restrict__ in_s, const float* __restrict__ wT_s, const float* __restrict__ b_s,
    float* __restrict__ outA_s, float* __restrict__ outB_s,
    const float* __restrict__ in_t, const float* __restrict__ wT_t, const float* __restrict__ b_t,
    float* __restrict__ outA_t, float* __restrict__ outB_t)
{
  const int tsel = blockIdx.y;
  const float* in   = tsel ? in_t  : in_s;
  const float* wT   = tsel ? wT_t  : wT_s;
  const float* bias = tsel ? b_t   : b_s;
  float* outA = tsel ? outA_t : outA_s;
  float* outB = tsel ? outB_t : outB_s;

  const int bx = blockIdx.x;
  const int b  = bx >> 4;
  const int y0 = (bx & 15) * 2;
  const int t  = threadIdx.x;
  const int x  = t & 31;
  const int cg = t >> 5;            // 0..7 -> co = cg*8..+7

  __shared__ float wch[4608];       // [cc][k9][co] = [8][9][64], flat
  __shared__ float inch[8][5][64];  // [ci_chunk][row][ix]

  float acc[2][8];
#pragma unroll
  for (int yy = 0; yy < 2; ++yy)
#pragma unroll
    for (int o = 0; o < 8; ++o) acc[yy][o] = 0.f;

  for (int ci0 = 0; ci0 < 128; ci0 += 8) {
    __syncthreads();
    // Weights: contiguous coalesced copy (layout matches LDS exactly)
    {
      const float* wsrc = wT + ci0 * 576;
#pragma unroll 4
      for (int r = 0; r < 18; ++r) {
        const int e = t + 256 * r;
        wch[e] = wsrc[e];
      }
    }
    // Inputs: 8 ci x 5 rows x 64 x, coalesced over x
#pragma unroll 2
    for (int r = 0; r < 10; ++r) {
      const int e = t + 256 * r;
      const int ix = e & 63;
      const int q = e >> 6;         // 0..39
      const int ry = q % 5;
      const int cc = q / 5;
      const int iy = 2 * y0 - 1 + ry;
      float v = 0.f;
      if (iy >= 0 && iy < 64) v = in[((b * 128 + ci0 + cc) * 64 + iy) * 64 + ix];
      inch[cc][ry][ix] = v;
    }
    __syncthreads();
#pragma unroll
    for (int cc = 0; cc < 8; ++cc) {
#pragma unroll
      for (int ky = 0; ky < 3; ++ky) {
#pragma unroll
        for (int kx = 0; kx < 3; ++kx) {
          const int ix = 2 * x + kx - 1;      // [-1, 63]
          float i0 = 0.f, i1 = 0.f;
          if (ix >= 0) {
            i0 = inch[cc][ky][ix];
            i1 = inch[cc][ky + 2][ix];
          }
          const int k9 = ky * 3 + kx;
          const float4 wa = *reinterpret_cast<const float4*>(&wch[(cc * 9 + k9) * 64 + cg * 8]);
          const float4 wb = *reinterpret_cast<const float4*>(&wch[(cc * 9 + k9) * 64 + cg * 8 + 4]);
          const float wv[8] = {wa.x, wa.y, wa.z, wa.w, wb.x, wb.y, wb.z, wb.w};
#pragma unroll
          for (int o = 0; o < 8; ++o) {
            acc[0][o] = fmaf(i0, wv[o], acc[0][o]);
            acc[1][o] = fmaf(i1, wv[o], acc[1][o]);
          }
        }
      }
    }
  }
#pragma unroll
  for (int o = 0; o < 8; ++o) {
    const int co = cg * 8 + o;
    const float bv = bias[co];
#pragma unroll
    for (int yy = 0; yy < 2; ++yy) {
      const int idx = (b * 64 + co) * 1024 + (y0 + yy) * 32 + x;
      const float val = acc[yy][o] + bv;
      outA[idx] = val;
      if (outB) outB[idx] = val;
    }
  }
}

// ---------------------------------------------------------------------------
// Generic out[g][64][1024] = W[g/wdiv][64][K] @ X[g][K][1024] + bias
// grid (G, 16): 64-col n-tiles. Optional scalar dual-write to out2 (unaligned ok).
// ---------------------------------------------------------------------------
__global__ __launch_bounds__(256) void gemm64_kernel(
    const float* __restrict__ W, int wstride, int wdiv,
    const float* __restrict__ X, int xstride,
    float* __restrict__ out, int ostride,
    float* __restrict__ out2, int o2stride,
    const float* __restrict__ bias, int bstride,
    int K)
{
  const int g  = blockIdx.x;
  const int n0 = blockIdx.y * 64;
  const float* Wg = W + (size_t)(g / wdiv) * wstride;
  const float* Xg = X + (size_t)g * xstride;
  const int t = threadIdx.x;
  __shared__ float Xs[32][64];
  __shared__ float Ws[32][64];
  const int tn = t & 15, cgp = t >> 4;
  const int n4 = tn * 4, co4 = cgp * 4;
  float acc[4][4] = {};

  for (int k0 = 0; k0 < K; k0 += 32) {
    {
      const int kk = t >> 4;
      const int nn = (t & 15) * 4;
      *reinterpret_cast<float4*>(&Xs[kk][nn]) =
          *reinterpret_cast<const float4*>(Xg + (size_t)(k0 + kk) * N_ + n0 + nn);
      *reinterpret_cast<float4*>(&Xs[kk + 16][nn]) =
          *reinterpret_cast<const float4*>(Xg + (size_t)(k0 + kk + 16) * N_ + n0 + nn);
    }
    {
      const int co = t & 63, q4 = t >> 6;
      const float* wp = Wg + (size_t)co * K + k0 + q4 * 8;
      const float4 a = *reinterpret_cast<const float4*>(wp);
      const float4 c = *reinterpret_cast<const float4*>(wp + 4);
      const int kb = q4 * 8;
      Ws[kb + 0][co] = a.x; Ws[kb + 1][co] = a.y; Ws[kb + 2][co] = a.z; Ws[kb + 3][co] = a.w;
      Ws[kb + 4][co] = c.x; Ws[kb + 5][co] = c.y; Ws[kb + 6][co] = c.z; Ws[kb + 7][co] = c.w;
    }
    __syncthreads();
#pragma unroll
    for (int kk = 0; kk < 32; ++kk) {
      const float4 xv = *reinterpret_cast<const float4*>(&Xs[kk][n4]);
      const float4 wv = *reinterpret_cast<const float4*>(&Ws[kk][co4]);
      const float xa[4] = {xv.x, xv.y, xv.z, xv.w};
      const float wa[4] = {wv.x, wv.y, wv.z, wv.w};
#pragma unroll
      for (int a = 0; a < 4; ++a)
#pragma unroll
        for (int b2 = 0; b2 < 4; ++b2)
          acc[a][b2] = fmaf(wa[a], xa[b2], acc[a][b2]);
    }
    __syncthreads();
  }

  float bv[4] = {0.f, 0.f, 0.f, 0.f};
  if (bias) {
    const float* bg = bias + (size_t)(g / wdiv) * bstride;
    bv[0] = bg[co4]; bv[1] = bg[co4 + 1]; bv[2] = bg[co4 + 2]; bv[3] = bg[co4 + 3];
  }
#pragma unroll
  for (int ii = 0; ii < 4; ++ii) {
    float4 o4;
    o4.x = acc[ii][0] + bv[ii]; o4.y = acc[ii][1] + bv[ii];
    o4.z = acc[ii][2] + bv[ii]; o4.w = acc[ii][3] + bv[ii];
    const int idx = (co4 + ii) * N_ + n0 + n4;
    *reinterpret_cast<float4*>(out + (size_t)g * ostride + idx) = o4;
    if (out2) {
      float* o2 = out2 + (size_t)g * o2stride + idx;
      o2[0] = o4.x; o2[1] = o4.y; o2[2] = o4.z; o2[3] = o4.w;
    }
  }
}

// ---------------------------------------------------------------------------
// e_cam[i,j,b][c][d] = sum_n T[i,b,c,n] * S[j,b,d,n];  also atomic raw-sum.
// grid 72 = (i,j,b)
// ---------------------------------------------------------------------------
__global__ __launch_bounds__(256) void ecam_kernel(
    const float* __restrict__ T, const float* __restrict__ S,
    float* __restrict__ ecam, float* __restrict__ esum_cam)
{
  const int bx = blockIdx.x;
  const int b = bx & 7;
  const int j = (bx >> 3) % 3;
  const int i = bx / 24;
  const float* Tg = T + (size_t)(i * 8 + b) * PLANE;
  const float* Sg = S + (size_t)(j * 8 + b) * PLANE;
  const int t = threadIdx.x;
  __shared__ float Ts[64 * 68];
  __shared__ float Ss[64 * 68];
  __shared__ float rs[4];
  float acc[4][4] = {};
  const int c0 = (t & 15) * 4, d0 = (t >> 4) * 4;

  for (int nb = 0; nb < 1024; nb += 64) {
    __syncthreads();
    {
      const int nn = t & 63, rb = t >> 6;
#pragma unroll
      for (int r = 0; r < 16; ++r) {
        const int row = rb * 16 + r;
        Ts[nn * 68 + row] = Tg[row * N_ + nb + nn];
        Ss[nn * 68 + row] = Sg[row * N_ + nb + nn];
      }
    }
    __syncthreads();
#pragma unroll 8
    for (int nn = 0; nn < 64; ++nn) {
      const float4 tv = *reinterpret_cast<const float4*>(&Ts[nn * 68 + c0]);
      const float4 sv = *reinterpret_cast<const float4*>(&Ss[nn * 68 + d0]);
      const float ta[4] = {tv.x, tv.y, tv.z, tv.w};
      const float sa[4] = {sv.x, sv.y, sv.z, sv.w};
#pragma unroll
      for (int ci = 0; ci < 4; ++ci)
#pragma unroll
        for (int di = 0; di < 4; ++di)
          acc[ci][di] = fmaf(ta[ci], sa[di], acc[ci][di]);
    }
  }
  float s = 0.f;
#pragma unroll
  for (int ci = 0; ci < 4; ++ci)
#pragma unroll
    for (int di = 0; di < 4; ++di) s += acc[ci][di];
  s = wred_sum(s);
  if ((t & 63) == 0) rs[t >> 6] = s;
  __syncthreads();
  if (t == 0) atomicAdd(esum_cam + i * 3 + j, rs[0] + rs[1] + rs[2] + rs[3]);

  float* eo = ecam + (size_t)((i * 3 + j) * 8 + b) * 4096;
#pragma unroll
  for (int ci = 0; ci < 4; ++ci) {
    float4 o4; o4.x = acc[ci][0]; o4.y = acc[ci][1]; o4.z = acc[ci][2]; o4.w = acc[ci][3];
    *reinterpret_cast<float4*>(eo + (c0 + ci) * 64 + d0) = o4;
  }
}

// ---------------------------------------------------------------------------
// attn_cam[i,b][c][d] = sum_j softmax_d(e_cam[i,j,b,c,:])[d]     grid 24
// ---------------------------------------------------------------------------
__global__ __launch_bounds__(256) void acam_kernel(
    const float* __restrict__ ecam, float* __restrict__ acam)
{
  const int bx = blockIdx.x;
  const int b = bx & 7, i = bx >> 3;
  const int t = threadIdx.x;
  const int c = t >> 2, seg = t & 3;
  float acc[16] = {};
#pragma unroll
  for (int j = 0; j < 3; ++j) {
    const float* e = ecam + (size_t)((i * 3 + j) * 8 + b) * 4096 + c * 64 + seg * 16;
    float ev[16];
#pragma unroll
    for (int r = 0; r < 4; ++r) {
      const float4 v4 = *reinterpret_cast<const float4*>(e + r * 4);
      ev[4 * r] = v4.x; ev[4 * r + 1] = v4.y; ev[4 * r + 2] = v4.z; ev[4 * r + 3] = v4.w;
    }
    float mx = ev[0];
#pragma unroll
    for (int r = 1; r < 16; ++r) mx = fmaxf(mx, ev[r]);
    mx = fmaxf(mx, __shfl_xor(mx, 1, 4));
    mx = fmaxf(mx, __shfl_xor(mx, 2, 4));
    float pv[16], ss = 0.f;
#pragma unroll
    for (int r = 0; r < 16; ++r) { pv[r] = __expf(ev[r] - mx); ss += pv[r]; }
    ss += __shfl_xor(ss, 1, 4);
    ss += __shfl_xor(ss, 2, 4);
    const float rc = 1.f / ss;
#pragma unroll
    for (int r = 0; r < 16; ++r) acc[r] += pv[r] * rc;
  }
  float* ao = acam + (size_t)(i * 8 + b) * 4096 + c * 64 + seg * 16;
#pragma unroll
  for (int r = 0; r < 4; ++r) {
    float4 o4; o4.x = acc[4 * r]; o4.y = acc[4 * r + 1]; o4.z = acc[4 * r + 2]; o4.w = acc[4 * r + 3];
    *reinterpret_cast<float4*>(ao + r * 4) = o4;
  }
}

// ---------------------------------------------------------------------------
// PAM: per (i,b,16-query tile): logits over all (j,m) with per-thread 4 m cols,
// softmax per j (wave+block reduce), Sum_j probs kept in regs, PV via LDS pT.
// grid 1536
// ---------------------------------------------------------------------------
__global__ __launch_bounds__(256, 2) void pam_kernel(
    const float* __restrict__ q, const float* __restrict__ k, const float* __restrict__ v,
    const float* __restrict__ ocam, float* __restrict__ tgts, float* __restrict__ esum_pam)
{
  const int bx = blockIdx.x;
  const int qt = bx & 63;
  const int b  = (bx >> 6) & 7;
  const int i  = bx >> 9;
  const int n0 = qt * 16;
  const int t = threadIdx.x;
  const int lane = t & 63;
  const int wv = t >> 6;

  __shared__ float pT[512][16];   // 32 KB, swizzled columns
  __shared__ float ub[2304];      // union: {qs[1024], redmx[64], redse[64], redes[4]} | vsT[32*72]
  float* qs    = ub;
  float* redmx = ub + 1024;
  float* redse = ub + 1088;
  float* redes = ub + 1152;

  const size_t ibo = (size_t)(i * 8 + b) * PLANE;
  const float* qg = q + ibo;
  for (int e = t; e < 1024; e += 256) {
    const int c = e >> 4, nn = e & 15;
    qs[c * 16 + nn] = qg[c * N_ + n0 + nn];
  }

  float pacc[4][16] = {};
  __syncthreads();

  for (int j = 0; j < 3; ++j) {
    const float* kg = k + (size_t)(j * 8 + b) * PLANE + 4 * t;
    float l[4][16] = {};
#pragma unroll 2
    for (int c = 0; c < 64; ++c) {
      const float4 kv = *reinterpret_cast<const float4*>(kg + c * N_);
      const float km[4] = {kv.x, kv.y, kv.z, kv.w};
      float qv[16];
      *reinterpret_cast<float4*>(&qv[0])  = *reinterpret_cast<const float4*>(&qs[c * 16 + 0]);
      *reinterpret_cast<float4*>(&qv[4])  = *reinterpret_cast<const float4*>(&qs[c * 16 + 4]);
      *reinterpret_cast<float4*>(&qv[8])  = *reinterpret_cast<const float4*>(&qs[c * 16 + 8]);
      *reinterpret_cast<float4*>(&qv[12]) = *reinterpret_cast<const float4*>(&qs[c * 16 + 12]);
#pragma unroll
      for (int mi = 0; mi < 4; ++mi)
#pragma unroll
        for (int ni = 0; ni < 16; ++ni)
          l[mi][ni] = fmaf(km[mi], qv[ni], l[mi][ni]);
    }
    // row maxes + raw logit sum
    float lm[16];
#pragma unroll
    for (int ni = 0; ni < 16; ++ni)
      lm[ni] = fmaxf(fmaxf(l[0][ni], l[1][ni]), fmaxf(l[2][ni], l[3][ni]));
#pragma unroll
    for (int ni = 0; ni < 16; ++ni) lm[ni] = wred_max(lm[ni]);
    float es = 0.f;
#pragma unroll
    for (int mi = 0; mi < 4; ++mi)
#pragma unroll
      for (int ni = 0; ni < 16; ++ni) es += l[mi][ni];
    es = wred_sum(es);
    if (lane == 0) {
#pragma unroll
      for (int ni = 0; ni < 16; ++ni) redmx[wv * 16 + ni] = lm[ni];
      redes[wv] = es;
    }
    __syncthreads();
    float mx[16];
#pragma unroll
    for (int ni = 0; ni < 16; ++ni)
      mx[ni] = fmaxf(fmaxf(redmx[ni], redmx[16 + ni]), fmaxf(redmx[32 + ni], redmx[48 + ni]));
    if (t == 0) atomicAdd(esum_pam + i * 3 + j, redes[0] + redes[1] + redes[2] + redes[3]);
    // exp + sums
    float se[16];
#pragma unroll
    for (int ni = 0; ni < 16; ++ni) se[ni] = 0.f;
#pragma unroll
    for (int mi = 0; mi < 4; ++mi)
#pragma unroll
      for (int ni = 0; ni < 16; ++ni) {
        l[mi][ni] = __expf(l[mi][ni] - mx[ni]);
        se[ni] += l[mi][ni];
      }
#pragma unroll
    for (int ni = 0; ni < 16; ++ni) se[ni] = wred_sum(se[ni]);
    if (lane == 0) {
#pragma unroll
      for (int ni = 0; ni < 16; ++ni) redse[wv * 16 + ni] = se[ni];
    }
    __syncthreads();
    float rse[16];
#pragma unroll
    for (int ni = 0; ni < 16; ++ni)
      rse[ni] = 1.f / (redse[ni] + redse[16 + ni] + redse[32 + ni] + redse[48 + ni]);
#pragma unroll
    for (int mi = 0; mi < 4; ++mi)
#pragma unroll
      for (int ni = 0; ni < 16; ++ni)
        pacc[mi][ni] += l[mi][ni] * rse[ni];
    __syncthreads();
  }

  // ---- PV: out[c][n] = sum_m v[c][m] * pacc[n][m], two 512-m halves ----
  const float* vg = v + ibo;
  float oacc[4][4] = {};
  const int mq  = lane >> 4;
  const int sub = lane & 15;
  const int c0  = wv * 16 + (sub & 3) * 4;
  const int nb  = (sub >> 2) * 4;
  float* vsT = ub;  // [32][72]

  for (int half = 0; half < 2; ++half) {
    __syncthreads();
    if ((t >> 7) == half) {
      const int tt = t & 127;
#pragma unroll
      for (int mi = 0; mi < 4; ++mi) {
        const int row = tt * 4 + mi;               // row within half
        const int sw = ((row >> 2) & 3) << 2;
#pragma unroll
        for (int gcol = 0; gcol < 16; gcol += 4) {
          float4 w4;
          w4.x = pacc[mi][gcol]; w4.y = pacc[mi][gcol + 1];
          w4.z = pacc[mi][gcol + 2]; w4.w = pacc[mi][gcol + 3];
          *reinterpret_cast<float4*>(&pT[row][gcol ^ sw]) = w4;
        }
      }
    }
    __syncthreads();
    for (int mc = 0; mc < 512; mc += 32) {
      const int mbase = half * 512 + mc;
      {
        const int nn = t & 31, rb = t >> 5;
#pragma unroll
        for (int r = 0; r < 8; ++r) {
          const int c = rb * 8 + r;
          vsT[nn * 72 + c] = vg[c * N_ + mbase + nn];
        }
      }
      __syncthreads();
#pragma unroll
      for (int mi = 0; mi < 8; ++mi) {
        const int mm = mi * 4 + mq;
        const int row = mc + mm;
        const int sw = ((row >> 2) & 3) << 2;
        const float4 pv = *reinterpret_cast<const float4*>(&pT[row][nb ^ sw]);
        const float4 vvv = *reinterpret_cast<const float4*>(&vsT[mm * 72 + c0]);
        const float pa[4] = {pv.x, pv.y, pv.z, pv.w};
        const float va[4] = {vvv.x, vvv.y, vvv.z, vvv.w};
#pragma unroll
        for (int ci = 0; ci < 4; ++ci)
#pragma unroll
          for (int ni = 0; ni < 4; ++ni)
            oacc[ci][ni] = fmaf(va[ci], pa[ni], oacc[ci][ni]);
      }
      __syncthreads();
    }
  }
  // reduce m-quarters (lanes mq 0..3 within wave)
#pragma unroll
  for (int ci = 0; ci < 4; ++ci)
#pragma unroll
    for (int ni = 0; ni < 4; ++ni) {
      oacc[ci][ni] += __shfl_xor(oacc[ci][ni], 16, 64);
      oacc[ci][ni] += __shfl_xor(oacc[ci][ni], 32, 64);
    }
  if (mq == 0) {
    const float* og = ocam + ibo;
    float* outg = tgts + (size_t)(2 * i * 8 + b) * PLANE;
#pragma unroll
    for (int ci = 0; ci < 4; ++ci)
#pragma unroll
      for (int ni = 0; ni < 4; ++ni) {
        const int idx = (c0 + ci) * N_ + n0 + nb + ni;
        outg[idx] = 0.5f * (oacc[ci][ni] + og[idx]);
      }
  }
}

// ---------------------------------------------------------------------------
// alpha[i][j] = 0.5*(softmax_j(mean e_pam) + softmax_j(mean e_cam))
// ---------------------------------------------------------------------------
__global__ void alpha_kernel(const float* __restrict__ esum, float* __restrict__ alpha)
{
  const int t = threadIdx.x;
  if (t >= 9) return;
  const int i = t / 3, j = t % 3;
  float p[3], c[3];
#pragma unroll
  for (int jj = 0; jj < 3; ++jj) {
    p[jj] = esum[i * 3 + jj] * (1.0f / 8388608.0f);
    c[jj] = esum[9 + i * 3 + jj] * (1.0f / 32768.0f);
  }
  const float mp = fmaxf(p[0], fmaxf(p[1], p[2]));
  const float mc = fmaxf(c[0], fmaxf(c[1], c[2]));
  float sp = 0.f, sc = 0.f;
#pragma unroll
  for (int jj = 0; jj < 3; ++jj) { sp += __expf(p[jj] - mp); sc += __expf(c[jj] - mc); }
  alpha[t] = 0.5f * (__expf(p[j] - mp) / sp + __expf(c[j] - mc) / sc);
}

// ---------------------------------------------------------------------------
extern "C" void kernel_launch(void* const* d_in, const int* in_sizes, int n_in,
                              void* d_out, int out_size, void* d_ws, size_t ws_size,
                              hipStream_t stream)
{
  const float* src0 = (const float*)d_in[0];
  const float* src1 = (const float*)d_in[1];
  const float* src2 = (const float*)d_in[2];
  const float* tgt0 = (const float*)d_in[3];
  const float* tgt1 = (const float*)d_in[4];
  const float* tgt2 = (const float*)d_in[5];
  const float* fs0_w = (const float*)d_in[6];  const float* fs0_b = (const float*)d_in[7];
  const float* fs1_w = (const float*)d_in[8];  const float* fs1_b = (const float*)d_in[9];
  const float* fs2_w = (const float*)d_in[10]; const float* fs2_b = (const float*)d_in[11];
  const float* ft0_w = (const float*)d_in[12]; const float* ft0_b = (const float*)d_in[13];
  const float* ft1_w = (const float*)d_in[14]; const float* ft1_b = (const float*)d_in[15];
  const float* ft2_w = (const float*)d_in[16]; const float* ft2_b = (const float*)d_in[17];
  const float* pq_w = (const float*)d_in[18];  const float* pq_b = (const float*)d_in[19];
  const float* pk_w = (const float*)d_in[20];  const float* pk_b = (const float*)d_in[21];
  const float* pv_w = (const float*)d_in[22];  const float* pv_b = (const float*)d_in[23];
  const float* cv_w = (const float*)d_in[24];  const float* cv_b = (const float*)d_in[25];

  float* out = (float*)d_out;
  float* S     = out;                 // srcs region doubles as S storage
  float* alpha = out + SZ;            // 9 floats
  float* tgts  = out + SZ + 9;        // [2L][B][PLANE]

  float* ws   = (float*)d_ws;
  float* T    = ws;
  float* qb   = ws + (size_t)SZ;
  float* kb   = ws + (size_t)2 * SZ;
  float* vb   = ws + (size_t)3 * SZ;
  float* vcb  = ws + (size_t)4 * SZ;
  float* ocam = ws + (size_t)5 * SZ;
  float* ecam = ws + (size_t)6 * SZ;                 // 294912
  float* acam = ws + (size_t)6 * SZ + 294912;        // 98304
  float* esum = ws + (size_t)6 * SZ + 393216;        // 18 (pam 9, cam 9)

  // Transposed conv0 weights live temporarily in qb (overwritten later by q proj)
  float* wTs = qb;
  float* wTt = qb + 73728;

  hipMemsetAsync(esum, 0, 18 * sizeof(float), stream);

  // Pre-transpose the 3x3 weights for coalesced, math-free LDS staging
  wtrans_kernel<<<dim3(288, 2), 256, 0, stream>>>(fs0_w, ft0_w, wTs, wTt);

  // Fit convs (S goes straight into d_out; T dual-written into tgts odd slots)
  conv0_kernel<<<dim3(128, 2), 256, 0, stream>>>(
      src0, wTs, fs0_b, S, nullptr,
      tgt0, wTt, ft0_b, T, tgts + (size_t)1 * BPL);
  gemm64_kernel<<<dim3(8, 16), 256, 0, stream>>>(fs1_w, 0, 1, src1, 256 * N_, S + BPL, PLANE,
                                                 nullptr, 0, fs1_b, 0, 256);
  gemm64_kernel<<<dim3(8, 16), 256, 0, stream>>>(fs2_w, 0, 1, src2, 512 * N_, S + 2 * BPL, PLANE,
                                                 nullptr, 0, fs2_b, 0, 512);
  gemm64_kernel<<<dim3(8, 16), 256, 0, stream>>>(ft1_w, 0, 1, tgt1, 256 * N_, T + BPL, PLANE,
                                                 tgts + (size_t)3 * BPL, PLANE, ft1_b, 0, 256);
  gemm64_kernel<<<dim3(8, 16), 256, 0, stream>>>(ft2_w, 0, 1, tgt2, 512 * N_, T + 2 * BPL, PLANE,
                                                 tgts + (size_t)5 * BPL, PLANE, ft2_b, 0, 512);

  // Projections q,k,v,vc
  gemm64_kernel<<<dim3(24, 16), 256, 0, stream>>>(pq_w, 4096, 8, T, PLANE, qb, PLANE,
                                                  nullptr, 0, pq_b, 64, 64);
  gemm64_kernel<<<dim3(24, 16), 256, 0, stream>>>(pk_w, 4096, 8, S, PLANE, kb, PLANE,
                                                  nullptr, 0, pk_b, 64, 64);
  gemm64_kernel<<<dim3(24, 16), 256, 0, stream>>>(pv_w, 4096, 8, T, PLANE, vb, PLANE,
                                                  nullptr, 0, pv_b, 64, 64);
  gemm64_kernel<<<dim3(24, 16), 256, 0, stream>>>(cv_w, 4096, 8, T, PLANE, vcb, PLANE,
                                                  nullptr, 0, cv_b, 64, 64);

  // CAM
  ecam_kernel<<<72, 256, 0, stream>>>(T, S, ecam, esum + 9);
  acam_kernel<<<24, 256, 0, stream>>>(ecam, acam);
  gemm64_kernel<<<dim3(24, 16), 256, 0, stream>>>(acam, 4096, 1, vcb, PLANE, ocam, PLANE,
                                                  nullptr, 0, nullptr, 0, 64);

  // PAM + fuse (writes tgts even slots = 0.5*(out_pam + out_cam))
  pam_kernel<<<1536, 256, 0, stream>>>(qb, kb, vb, ocam, tgts, esum);

  alpha_kernel<<<1, 64, 0, stream>>>(esum, alpha);
}

// Round 4
// 553.136 us; speedup vs baseline: 1.6884x; 1.6556x over previous
//
#include <hip/hip_runtime.h>

// Problem constants
static constexpr int L_ = 3, B_ = 8, C_ = 64, N_ = 1024;
static constexpr int PLANE = C_ * N_;       // 65536
static constexpr int SZ    = L_ * B_ * PLANE; // 1572864 (srcs size, also per-stack-slot count)
static constexpr int BPL   = B_ * PLANE;    // 524288

#define DI __device__ __forceinline__

DI float wred_max(float v) {
#pragma unroll
  for (int m = 1; m < 64; m <<= 1) v = fmaxf(v, __shfl_xor(v, m, 64));
  return v;
}
DI float wred_sum(float v) {
#pragma unroll
  for (int m = 1; m < 64; m <<= 1) v += __shfl_xor(v, m, 64);
  return v;
}

// ---------------------------------------------------------------------------
// Weight transpose: w[co][ci][k9] -> wT[ci][k9][co]  (64 x 128 x 9 each)
// grid (288, 2)
// ---------------------------------------------------------------------------
__global__ __launch_bounds__(256) void wtrans_kernel(
    const float* __restrict__ w_s, const float* __restrict__ w_t,
    float* __restrict__ wT_s, float* __restrict__ wT_t)
{
  const float* w = blockIdx.y ? w_t : w_s;
  float* wT = blockIdx.y ? wT_t : wT_s;
  const int e = blockIdx.x * 256 + threadIdx.x;   // 0..73727
  const int co = e & 63;
  const int q = e >> 6;
  const int k9 = q % 9;
  const int ci = q / 9;
  wT[e] = w[(co * 128 + ci) * 9 + k9];
}

// ---------------------------------------------------------------------------
// conv0: 3x3 stride-2 pad-1, Cin=128 -> Cout=64, 64x64 -> 32x32.
// grid (128, 2): x = b*16 + 2-row slab, y selects (src,tgt).
// Weights pre-transposed as wT[ci][k9][co] so staging is a flat copy.
// cc loop is unroll-1: bounds LLVM's LDS-load hoisting scope (256-VGPR spill
// observed with full unroll: 871 MB scratch writes/dispatch).
// ---------------------------------------------------------------------------
__global__ __launch_bounds__(256) void conv0_kernel(
    const float* __restrict__ in_s, const float* __restrict__ wT_s, const float* __restrict__ b_s,
    float* __restrict__ outA_s, float* __restrict__ outB_s,
    const float* __restrict__ in_t, const float* __restrict__ wT_t, const float* __restrict__ b_t,
    float* __restrict__ outA_t, float* __restrict__ outB_t)
{
  const int tsel = blockIdx.y;
  const float* in   = tsel ? in_t  : in_s;
  const float* wT   = tsel ? wT_t  : wT_s;
  const float* bias = tsel ? b_t   : b_s;
  float* outA = tsel ? outA_t : outA_s;
  float* outB = tsel ? outB_t : outB_s;

  const int bx = blockIdx.x;
  const int b  = bx >> 4;
  const int y0 = (bx & 15) * 2;
  const int t  = threadIdx.x;
  const int x  = t & 31;
  const int cg = t >> 5;            // 0..7 -> co = cg*8..+7

  __shared__ float wch[4608];       // [cc][k9][co] = [8][9][64], flat
  __shared__ float inch[8][5][64];  // [ci_chunk][row][ix]

  float acc[2][8];
#pragma unroll
  for (int yy = 0; yy < 2; ++yy)
#pragma unroll
    for (int o = 0; o < 8; ++o) acc[yy][o] = 0.f;

  for (int ci0 = 0; ci0 < 128; ci0 += 8) {
    __syncthreads();
    // Weights: contiguous coalesced copy (layout matches LDS exactly)
    {
      const float* wsrc = wT + ci0 * 576;
#pragma unroll 4
      for (int r = 0; r < 18; ++r) {
        const int e = t + 256 * r;
        wch[e] = wsrc[e];
      }
    }
    // Inputs: 8 ci x 5 rows x 64 x, coalesced over x
#pragma unroll 2
    for (int r = 0; r < 10; ++r) {
      const int e = t + 256 * r;
      const int ix = e & 63;
      const int q = e >> 6;         // 0..39
      const int ry = q % 5;
      const int cc = q / 5;
      const int iy = 2 * y0 - 1 + ry;
      float v = 0.f;
      if (iy >= 0 && iy < 64) v = in[((b * 128 + ci0 + cc) * 64 + iy) * 64 + ix];
      inch[cc][ry][ix] = v;
    }
    __syncthreads();
#pragma unroll 1
    for (int cc = 0; cc < 8; ++cc) {
      // 15 distinct input scalars for this (thread, ci): rows 0..4, kx 0..2
      float iv[5][3];
#pragma unroll
      for (int ry = 0; ry < 5; ++ry) {
#pragma unroll
        for (int kx = 0; kx < 3; ++kx) {
          const int ix = 2 * x + kx - 1;   // [-1, 63]
          iv[ry][kx] = (ix >= 0) ? inch[cc][ry][ix] : 0.f;
        }
      }
#pragma unroll
      for (int ky = 0; ky < 3; ++ky) {
#pragma unroll
        for (int kx = 0; kx < 3; ++kx) {
          const int k9 = ky * 3 + kx;
          const float4 wa = *reinterpret_cast<const float4*>(&wch[(cc * 9 + k9) * 64 + cg * 8]);
          const float4 wb = *reinterpret_cast<const float4*>(&wch[(cc * 9 + k9) * 64 + cg * 8 + 4]);
          const float wv[8] = {wa.x, wa.y, wa.z, wa.w, wb.x, wb.y, wb.z, wb.w};
          const float i0 = iv[ky][kx];
          const float i1 = iv[ky + 2][kx];
#pragma unroll
          for (int o = 0; o < 8; ++o) {
            acc[0][o] = fmaf(i0, wv[o], acc[0][o]);
            acc[1][o] = fmaf(i1, wv[o], acc[1][o]);
          }
        }
      }
    }
  }
#pragma unroll
  for (int o = 0; o < 8; ++o) {
    const int co = cg * 8 + o;
    const float bv = bias[co];
#pragma unroll
    for (int yy = 0; yy < 2; ++yy) {
      const int idx = (b * 64 + co) * 1024 + (y0 + yy) * 32 + x;
      const float val = acc[yy][o] + bv;
      outA[idx] = val;
      if (outB) outB[idx] = val;
    }
  }
}

// ---------------------------------------------------------------------------
// Generic out[g][64][1024] = W[g/wdiv][64][K] @ X[g][K][1024] + bias
// grid (G, 16): 64-col n-tiles. Optional scalar dual-write to out2 (unaligned ok).
// ---------------------------------------------------------------------------
__global__ __launch_bounds__(256) void gemm64_kernel(
    const float* __restrict__ W, int wstride, int wdiv,
    const float* __restrict__ X, int xstride,
    float* __restrict__ out, int ostride,
    float* __restrict__ out2, int o2stride,
    const float* __restrict__ bias, int bstride,
    int K)
{
  const int g  = blockIdx.x;
  const int n0 = blockIdx.y * 64;
  const float* Wg = W + (size_t)(g / wdiv) * wstride;
  const float* Xg = X + (size_t)g * xstride;
  const int t = threadIdx.x;
  __shared__ float Xs[32][64];
  __shared__ float Ws[32][64];
  const int tn = t & 15, cgp = t >> 4;
  const int n4 = tn * 4, co4 = cgp * 4;
  float acc[4][4] = {};

  for (int k0 = 0; k0 < K; k0 += 32) {
    {
      const int kk = t >> 4;
      const int nn = (t & 15) * 4;
      *reinterpret_cast<float4*>(&Xs[kk][nn]) =
          *reinterpret_cast<const float4*>(Xg + (size_t)(k0 + kk) * N_ + n0 + nn);
      *reinterpret_cast<float4*>(&Xs[kk + 16][nn]) =
          *reinterpret_cast<const float4*>(Xg + (size_t)(k0 + kk + 16) * N_ + n0 + nn);
    }
    {
      const int co = t & 63, q4 = t >> 6;
      const float* wp = Wg + (size_t)co * K + k0 + q4 * 8;
      const float4 a = *reinterpret_cast<const float4*>(wp);
      const float4 c = *reinterpret_cast<const float4*>(wp + 4);
      const int kb = q4 * 8;
      Ws[kb + 0][co] = a.x; Ws[kb + 1][co] = a.y; Ws[kb + 2][co] = a.z; Ws[kb + 3][co] = a.w;
      Ws[kb + 4][co] = c.x; Ws[kb + 5][co] = c.y; Ws[kb + 6][co] = c.z; Ws[kb + 7][co] = c.w;
    }
    __syncthreads();
#pragma unroll
    for (int kk = 0; kk < 32; ++kk) {
      const float4 xv = *reinterpret_cast<const float4*>(&Xs[kk][n4]);
      const float4 wv = *reinterpret_cast<const float4*>(&Ws[kk][co4]);
      const float xa[4] = {xv.x, xv.y, xv.z, xv.w};
      const float wa[4] = {wv.x, wv.y, wv.z, wv.w};
#pragma unroll
      for (int a = 0; a < 4; ++a)
#pragma unroll
        for (int b2 = 0; b2 < 4; ++b2)
          acc[a][b2] = fmaf(wa[a], xa[b2], acc[a][b2]);
    }
    __syncthreads();
  }

  float bv[4] = {0.f, 0.f, 0.f, 0.f};
  if (bias) {
    const float* bg = bias + (size_t)(g / wdiv) * bstride;
    bv[0] = bg[co4]; bv[1] = bg[co4 + 1]; bv[2] = bg[co4 + 2]; bv[3] = bg[co4 + 3];
  }
#pragma unroll
  for (int ii = 0; ii < 4; ++ii) {
    float4 o4;
    o4.x = acc[ii][0] + bv[ii]; o4.y = acc[ii][1] + bv[ii];
    o4.z = acc[ii][2] + bv[ii]; o4.w = acc[ii][3] + bv[ii];
    const int idx = (co4 + ii) * N_ + n0 + n4;
    *reinterpret_cast<float4*>(out + (size_t)g * ostride + idx) = o4;
    if (out2) {
      float* o2 = out2 + (size_t)g * o2stride + idx;
      o2[0] = o4.x; o2[1] = o4.y; o2[2] = o4.z; o2[3] = o4.w;
    }
  }
}

// ---------------------------------------------------------------------------
// e_cam[i,j,b][c][d] = sum_n T[i,b,c,n] * S[j,b,d,n];  also atomic raw-sum.
// grid 72 = (i,j,b)
// ---------------------------------------------------------------------------
__global__ __launch_bounds__(256) void ecam_kernel(
    const float* __restrict__ T, const float* __restrict__ S,
    float* __restrict__ ecam, float* __restrict__ esum_cam)
{
  const int bx = blockIdx.x;
  const int b = bx & 7;
  const int j = (bx >> 3) % 3;
  const int i = bx / 24;
  const float* Tg = T + (size_t)(i * 8 + b) * PLANE;
  const float* Sg = S + (size_t)(j * 8 + b) * PLANE;
  const int t = threadIdx.x;
  __shared__ float Ts[64 * 68];
  __shared__ float Ss[64 * 68];
  __shared__ float rs[4];
  float acc[4][4] = {};
  const int c0 = (t & 15) * 4, d0 = (t >> 4) * 4;

  for (int nb = 0; nb < 1024; nb += 64) {
    __syncthreads();
    {
      const int nn = t & 63, rb = t >> 6;
#pragma unroll
      for (int r = 0; r < 16; ++r) {
        const int row = rb * 16 + r;
        Ts[nn * 68 + row] = Tg[row * N_ + nb + nn];
        Ss[nn * 68 + row] = Sg[row * N_ + nb + nn];
      }
    }
    __syncthreads();
#pragma unroll 8
    for (int nn = 0; nn < 64; ++nn) {
      const float4 tv = *reinterpret_cast<const float4*>(&Ts[nn * 68 + c0]);
      const float4 sv = *reinterpret_cast<const float4*>(&Ss[nn * 68 + d0]);
      const float ta[4] = {tv.x, tv.y, tv.z, tv.w};
      const float sa[4] = {sv.x, sv.y, sv.z, sv.w};
#pragma unroll
      for (int ci = 0; ci < 4; ++ci)
#pragma unroll
        for (int di = 0; di < 4; ++di)
          acc[ci][di] = fmaf(ta[ci], sa[di], acc[ci][di]);
    }
  }
  float s = 0.f;
#pragma unroll
  for (int ci = 0; ci < 4; ++ci)
#pragma unroll
    for (int di = 0; di < 4; ++di) s += acc[ci][di];
  s = wred_sum(s);
  if ((t & 63) == 0) rs[t >> 6] = s;
  __syncthreads();
  if (t == 0) atomicAdd(esum_cam + i * 3 + j, rs[0] + rs[1] + rs[2] + rs[3]);

  float* eo = ecam + (size_t)((i * 3 + j) * 8 + b) * 4096;
#pragma unroll
  for (int ci = 0; ci < 4; ++ci) {
    float4 o4; o4.x = acc[ci][0]; o4.y = acc[ci][1]; o4.z = acc[ci][2]; o4.w = acc[ci][3];
    *reinterpret_cast<float4*>(eo + (c0 + ci) * 64 + d0) = o4;
  }
}

// ---------------------------------------------------------------------------
// attn_cam[i,b][c][d] = sum_j softmax_d(e_cam[i,j,b,c,:])[d]     grid 24
// ---------------------------------------------------------------------------
__global__ __launch_bounds__(256) void acam_kernel(
    const float* __restrict__ ecam, float* __restrict__ acam)
{
  const int bx = blockIdx.x;
  const int b = bx & 7, i = bx >> 3;
  const int t = threadIdx.x;
  const int c = t >> 2, seg = t & 3;
  float acc[16] = {};
#pragma unroll
  for (int j = 0; j < 3; ++j) {
    const float* e = ecam + (size_t)((i * 3 + j) * 8 + b) * 4096 + c * 64 + seg * 16;
    float ev[16];
#pragma unroll
    for (int r = 0; r < 4; ++r) {
      const float4 v4 = *reinterpret_cast<const float4*>(e + r * 4);
      ev[4 * r] = v4.x; ev[4 * r + 1] = v4.y; ev[4 * r + 2] = v4.z; ev[4 * r + 3] = v4.w;
    }
    float mx = ev[0];
#pragma unroll
    for (int r = 1; r < 16; ++r) mx = fmaxf(mx, ev[r]);
    mx = fmaxf(mx, __shfl_xor(mx, 1, 4));
    mx = fmaxf(mx, __shfl_xor(mx, 2, 4));
    float pv[16], ss = 0.f;
#pragma unroll
    for (int r = 0; r < 16; ++r) { pv[r] = __expf(ev[r] - mx); ss += pv[r]; }
    ss += __shfl_xor(ss, 1, 4);
    ss += __shfl_xor(ss, 2, 4);
    const float rc = 1.f / ss;
#pragma unroll
    for (int r = 0; r < 16; ++r) acc[r] += pv[r] * rc;
  }
  float* ao = acam + (size_t)(i * 8 + b) * 4096 + c * 64 + seg * 16;
#pragma unroll
  for (int r = 0; r < 4; ++r) {
    float4 o4; o4.x = acc[4 * r]; o4.y = acc[4 * r + 1]; o4.z = acc[4 * r + 2]; o4.w = acc[4 * r + 3];
    *reinterpret_cast<float4*>(ao + r * 4) = o4;
  }
}

// ---------------------------------------------------------------------------
// PAM: per (i,b,16-query tile): logits over all (j,m) with per-thread 4 m cols,
// softmax per j (wave+block reduce), Sum_j probs kept in regs, PV via LDS pT.
// grid 1536
// ---------------------------------------------------------------------------
__global__ __launch_bounds__(256, 2) void pam_kernel(
    const float* __restrict__ q, const float* __restrict__ k, const float* __restrict__ v,
    const float* __restrict__ ocam, float* __restrict__ tgts, float* __restrict__ esum_pam)
{
  const int bx = blockIdx.x;
  const int qt = bx & 63;
  const int b  = (bx >> 6) & 7;
  const int i  = bx >> 9;
  const int n0 = qt * 16;
  const int t = threadIdx.x;
  const int lane = t & 63;
  const int wv = t >> 6;

  __shared__ float pT[512][16];   // 32 KB, swizzled columns
  __shared__ float ub[2304];      // union: {qs[1024], redmx[64], redse[64], redes[4]} | vsT[32*72]
  float* qs    = ub;
  float* redmx = ub + 1024;
  float* redse = ub + 1088;
  float* redes = ub + 1152;

  const size_t ibo = (size_t)(i * 8 + b) * PLANE;
  const float* qg = q + ibo;
  for (int e = t; e < 1024; e += 256) {
    const int c = e >> 4, nn = e & 15;
    qs[c * 16 + nn] = qg[c * N_ + n0 + nn];
  }

  float pacc[4][16] = {};
  __syncthreads();

  for (int j = 0; j < 3; ++j) {
    const float* kg = k + (size_t)(j * 8 + b) * PLANE + 4 * t;
    float l[4][16] = {};
#pragma unroll 2
    for (int c = 0; c < 64; ++c) {
      const float4 kv = *reinterpret_cast<const float4*>(kg + c * N_);
      const float km[4] = {kv.x, kv.y, kv.z, kv.w};
      float qv[16];
      *reinterpret_cast<float4*>(&qv[0])  = *reinterpret_cast<const float4*>(&qs[c * 16 + 0]);
      *reinterpret_cast<float4*>(&qv[4])  = *reinterpret_cast<const float4*>(&qs[c * 16 + 4]);
      *reinterpret_cast<float4*>(&qv[8])  = *reinterpret_cast<const float4*>(&qs[c * 16 + 8]);
      *reinterpret_cast<float4*>(&qv[12]) = *reinterpret_cast<const float4*>(&qs[c * 16 + 12]);
#pragma unroll
      for (int mi = 0; mi < 4; ++mi)
#pragma unroll
        for (int ni = 0; ni < 16; ++ni)
          l[mi][ni] = fmaf(km[mi], qv[ni], l[mi][ni]);
    }
    // row maxes + raw logit sum
    float lm[16];
#pragma unroll
    for (int ni = 0; ni < 16; ++ni)
      lm[ni] = fmaxf(fmaxf(l[0][ni], l[1][ni]), fmaxf(l[2][ni], l[3][ni]));
#pragma unroll
    for (int ni = 0; ni < 16; ++ni) lm[ni] = wred_max(lm[ni]);
    float es = 0.f;
#pragma unroll
    for (int mi = 0; mi < 4; ++mi)
#pragma unroll
      for (int ni = 0; ni < 16; ++ni) es += l[mi][ni];
    es = wred_sum(es);
    if (lane == 0) {
#pragma unroll
      for (int ni = 0; ni < 16; ++ni) redmx[wv * 16 + ni] = lm[ni];
      redes[wv] = es;
    }
    __syncthreads();
    float mx[16];
#pragma unroll
    for (int ni = 0; ni < 16; ++ni)
      mx[ni] = fmaxf(fmaxf(redmx[ni], redmx[16 + ni]), fmaxf(redmx[32 + ni], redmx[48 + ni]));
    if (t == 0) atomicAdd(esum_pam + i * 3 + j, redes[0] + redes[1] + redes[2] + redes[3]);
    // exp + sums
    float se[16];
#pragma unroll
    for (int ni = 0; ni < 16; ++ni) se[ni] = 0.f;
#pragma unroll
    for (int mi = 0; mi < 4; ++mi)
#pragma unroll
      for (int ni = 0; ni < 16; ++ni) {
        l[mi][ni] = __expf(l[mi][ni] - mx[ni]);
        se[ni] += l[mi][ni];
      }
#pragma unroll
    for (int ni = 0; ni < 16; ++ni) se[ni] = wred_sum(se[ni]);
    if (lane == 0) {
#pragma unroll
      for (int ni = 0; ni < 16; ++ni) redse[wv * 16 + ni] = se[ni];
    }
    __syncthreads();
    float rse[16];
#pragma unroll
    for (int ni = 0; ni < 16; ++ni)
      rse[ni] = 1.f / (redse[ni] + redse[16 + ni] + redse[32 + ni] + redse[48 + ni]);
#pragma unroll
    for (int mi = 0; mi < 4; ++mi)
#pragma unroll
      for (int ni = 0; ni < 16; ++ni)
        pacc[mi][ni] += l[mi][ni] * rse[ni];
    __syncthreads();
  }

  // ---- PV: out[c][n] = sum_m v[c][m] * pacc[n][m], two 512-m halves ----
  const float* vg = v + ibo;
  float oacc[4][4] = {};
  const int mq  = lane >> 4;
  const int sub = lane & 15;
  const int c0  = wv * 16 + (sub & 3) * 4;
  const int nb  = (sub >> 2) * 4;
  float* vsT = ub;  // [32][72]

  for (int half = 0; half < 2; ++half) {
    __syncthreads();
    if ((t >> 7) == half) {
      const int tt = t & 127;
#pragma unroll
      for (int mi = 0; mi < 4; ++mi) {
        const int row = tt * 4 + mi;               // row within half
        const int sw = ((row >> 2) & 3) << 2;
#pragma unroll
        for (int gcol = 0; gcol < 16; gcol += 4) {
          float4 w4;
          w4.x = pacc[mi][gcol]; w4.y = pacc[mi][gcol + 1];
          w4.z = pacc[mi][gcol + 2]; w4.w = pacc[mi][gcol + 3];
          *reinterpret_cast<float4*>(&pT[row][gcol ^ sw]) = w4;
        }
      }
    }
    __syncthreads();
    for (int mc = 0; mc < 512; mc += 32) {
      const int mbase = half * 512 + mc;
      {
        const int nn = t & 31, rb = t >> 5;
#pragma unroll
        for (int r = 0; r < 8; ++r) {
          const int c = rb * 8 + r;
          vsT[nn * 72 + c] = vg[c * N_ + mbase + nn];
        }
      }
      __syncthreads();
#pragma unroll
      for (int mi = 0; mi < 8; ++mi) {
        const int mm = mi * 4 + mq;
        const int row = mc + mm;
        const int sw = ((row >> 2) & 3) << 2;
        const float4 pv = *reinterpret_cast<const float4*>(&pT[row][nb ^ sw]);
        const float4 vvv = *reinterpret_cast<const float4*>(&vsT[mm * 72 + c0]);
        const float pa[4] = {pv.x, pv.y, pv.z, pv.w};
        const float va[4] = {vvv.x, vvv.y, vvv.z, vvv.w};
#pragma unroll
        for (int ci = 0; ci < 4; ++ci)
#pragma unroll
          for (int ni = 0; ni < 4; ++ni)
            oacc[ci][ni] = fmaf(va[ci], pa[ni], oacc[ci][ni]);
      }
      __syncthreads();
    }
  }
  // reduce m-quarters (lanes mq 0..3 within wave)
#pragma unroll
  for (int ci = 0; ci < 4; ++ci)
#pragma unroll
    for (int ni = 0; ni < 4; ++ni) {
      oacc[ci][ni] += __shfl_xor(oacc[ci][ni], 16, 64);
      oacc[ci][ni] += __shfl_xor(oacc[ci][ni], 32, 64);
    }
  if (mq == 0) {
    const float* og = ocam + ibo;
    float* outg = tgts + (size_t)(2 * i * 8 + b) * PLANE;
#pragma unroll
    for (int ci = 0; ci < 4; ++ci)
#pragma unroll
      for (int ni = 0; ni < 4; ++ni) {
        const int idx = (c0 + ci) * N_ + n0 + nb + ni;
        outg[idx] = 0.5f * (oacc[ci][ni] + og[idx]);
      }
  }
}

// ---------------------------------------------------------------------------
// alpha[i][j] = 0.5*(softmax_j(mean e_pam) + softmax_j(mean e_cam))
// ---------------------------------------------------------------------------
__global__ void alpha_kernel(const float* __restrict__ esum, float* __restrict__ alpha)
{
  const int t = threadIdx.x;
  if (t >= 9) return;
  const int i = t / 3, j = t % 3;
  float p[3], c[3];
#pragma unroll
  for (int jj = 0; jj < 3; ++jj) {
    p[jj] = esum[i * 3 + jj] * (1.0f / 8388608.0f);
    c[jj] = esum[9 + i * 3 + jj] * (1.0f / 32768.0f);
  }
  const float mp = fmaxf(p[0], fmaxf(p[1], p[2]));
  const float mc = fmaxf(c[0], fmaxf(c[1], c[2]));
  float sp = 0.f, sc = 0.f;
#pragma unroll
  for (int jj = 0; jj < 3; ++jj) { sp += __expf(p[jj] - mp); sc += __expf(c[jj] - mc); }
  alpha[t] = 0.5f * (__expf(p[j] - mp) / sp + __expf(c[j] - mc) / sc);
}

// ---------------------------------------------------------------------------
extern "C" void kernel_launch(void* const* d_in, const int* in_sizes, int n_in,
                              void* d_out, int out_size, void* d_ws, size_t ws_size,
                              hipStream_t stream)
{
  const float* src0 = (const float*)d_in[0];
  const float* src1 = (const float*)d_in[1];
  const float* src2 = (const float*)d_in[2];
  const float* tgt0 = (const float*)d_in[3];
  const float* tgt1 = (const float*)d_in[4];
  const float* tgt2 = (const float*)d_in[5];
  const float* fs0_w = (const float*)d_in[6];  const float* fs0_b = (const float*)d_in[7];
  const float* fs1_w = (const float*)d_in[8];  const float* fs1_b = (const float*)d_in[9];
  const float* fs2_w = (const float*)d_in[10]; const float* fs2_b = (const float*)d_in[11];
  const float* ft0_w = (const float*)d_in[12]; const float* ft0_b = (const float*)d_in[13];
  const float* ft1_w = (const float*)d_in[14]; const float* ft1_b = (const float*)d_in[15];
  const float* ft2_w = (const float*)d_in[16]; const float* ft2_b = (const float*)d_in[17];
  const float* pq_w = (const float*)d_in[18];  const float* pq_b = (const float*)d_in[19];
  const float* pk_w = (const float*)d_in[20];  const float* pk_b = (const float*)d_in[21];
  const float* pv_w = (const float*)d_in[22];  const float* pv_b = (const float*)d_in[23];
  const float* cv_w = (const float*)d_in[24];  const float* cv_b = (const float*)d_in[25];

  float* out = (float*)d_out;
  float* S     = out;                 // srcs region doubles as S storage
  float* alpha = out + SZ;            // 9 floats
  float* tgts  = out + SZ + 9;        // [2L][B][PLANE]

  float* ws   = (float*)d_ws;
  float* T    = ws;
  float* qb   = ws + (size_t)SZ;
  float* kb   = ws + (size_t)2 * SZ;
  float* vb   = ws + (size_t)3 * SZ;
  float* vcb  = ws + (size_t)4 * SZ;
  float* ocam = ws + (size_t)5 * SZ;
  float* ecam = ws + (size_t)6 * SZ;                 // 294912
  float* acam = ws + (size_t)6 * SZ + 294912;        // 98304
  float* esum = ws + (size_t)6 * SZ + 393216;        // 18 (pam 9, cam 9)

  // Transposed conv0 weights live temporarily in qb (overwritten later by q proj)
  float* wTs = qb;
  float* wTt = qb + 73728;

  hipMemsetAsync(esum, 0, 18 * sizeof(float), stream);

  // Pre-transpose the 3x3 weights for coalesced, math-free LDS staging
  wtrans_kernel<<<dim3(288, 2), 256, 0, stream>>>(fs0_w, ft0_w, wTs, wTt);

  // Fit convs (S goes straight into d_out; T dual-written into tgts odd slots)
  conv0_kernel<<<dim3(128, 2), 256, 0, stream>>>(
      src0, wTs, fs0_b, S, nullptr,
      tgt0, wTt, ft0_b, T, tgts + (size_t)1 * BPL);
  gemm64_kernel<<<dim3(8, 16), 256, 0, stream>>>(fs1_w, 0, 1, src1, 256 * N_, S + BPL, PLANE,
                                                 nullptr, 0, fs1_b, 0, 256);
  gemm64_kernel<<<dim3(8, 16), 256, 0, stream>>>(fs2_w, 0, 1, src2, 512 * N_, S + 2 * BPL, PLANE,
                                                 nullptr, 0, fs2_b, 0, 512);
  gemm64_kernel<<<dim3(8, 16), 256, 0, stream>>>(ft1_w, 0, 1, tgt1, 256 * N_, T + BPL, PLANE,
                                                 tgts + (size_t)3 * BPL, PLANE, ft1_b, 0, 256);
  gemm64_kernel<<<dim3(8, 16), 256, 0, stream>>>(ft2_w, 0, 1, tgt2, 512 * N_, T + 2 * BPL, PLANE,
                                                 tgts + (size_t)5 * BPL, PLANE, ft2_b, 0, 512);

  // Projections q,k,v,vc
  gemm64_kernel<<<dim3(24, 16), 256, 0, stream>>>(pq_w, 4096, 8, T, PLANE, qb, PLANE,
                                                  nullptr, 0, pq_b, 64, 64);
  gemm64_kernel<<<dim3(24, 16), 256, 0, stream>>>(pk_w, 4096, 8, S, PLANE, kb, PLANE,
                                                  nullptr, 0, pk_b, 64, 64);
  gemm64_kernel<<<dim3(24, 16), 256, 0, stream>>>(pv_w, 4096, 8, T, PLANE, vb, PLANE,
                                                  nullptr, 0, pv_b, 64, 64);
  gemm64_kernel<<<dim3(24, 16), 256, 0, stream>>>(cv_w, 4096, 8, T, PLANE, vcb, PLANE,
                                                  nullptr, 0, cv_b, 64, 64);

  // CAM
  ecam_kernel<<<72, 256, 0, stream>>>(T, S, ecam, esum + 9);
  acam_kernel<<<24, 256, 0, stream>>>(ecam, acam);
  gemm64_kernel<<<dim3(24, 16), 256, 0, stream>>>(acam, 4096, 1, vcb, PLANE, ocam, PLANE,
                                                  nullptr, 0, nullptr, 0, 64);

  // PAM + fuse (writes tgts even slots = 0.5*(out_pam + out_cam))
  pam_kernel<<<1536, 256, 0, stream>>>(qb, kb, vb, ocam, tgts, esum);

  alpha_kernel<<<1, 64, 0, stream>>>(esum, alpha);
}

// Round 5
// 466.631 us; speedup vs baseline: 2.0015x; 1.1854x over previous
//
#include <hip/hip_runtime.h>

// Problem constants
static constexpr int L_ = 3, B_ = 8, C_ = 64, N_ = 1024;
static constexpr int PLANE = C_ * N_;       // 65536
static constexpr int SZ    = L_ * B_ * PLANE; // 1572864 (srcs size, also per-stack-slot count)
static constexpr int BPL   = B_ * PLANE;    // 524288

#define DI __device__ __forceinline__

typedef __attribute__((ext_vector_type(8))) short short8;   // 8 bf16 (MFMA A/B frag)
typedef __attribute__((ext_vector_type(4))) float f32x4;    // MFMA C/D frag
typedef unsigned int uint32;
typedef unsigned short ushort16_t;

DI float wred_max(float v) {
#pragma unroll
  for (int m = 1; m < 64; m <<= 1) v = fmaxf(v, __shfl_xor(v, m, 64));
  return v;
}
DI float wred_sum(float v) {
#pragma unroll
  for (int m = 1; m < 64; m <<= 1) v += __shfl_xor(v, m, 64);
  return v;
}

// bf16 helpers (RNE)
DI unsigned short f2bf(float f) {
  uint32 u = __builtin_bit_cast(uint32, f);
  return (unsigned short)((u + 0x7FFFu + ((u >> 16) & 1u)) >> 16);
}
DI float bf2f(unsigned short h) {
  uint32 u = ((uint32)h) << 16;
  return __builtin_bit_cast(float, u);
}
DI uint32 pkbf(float a, float b) {
  return (uint32)f2bf(a) | ((uint32)f2bf(b) << 16);
}
DI short8 bcs8(uint4 v) { return __builtin_bit_cast(short8, v); }

DI f32x4 mfma16(short8 a, short8 b, f32x4 c) {
  return __builtin_amdgcn_mfma_f32_16x16x32_bf16(a, b, c, 0, 0, 0);
}

// ---------------------------------------------------------------------------
// Weight transpose: w[co][ci][k9] -> wT[ci][k9][co]  (64 x 128 x 9 each)
// grid (288, 2)
// ---------------------------------------------------------------------------
__global__ __launch_bounds__(256) void wtrans_kernel(
    const float* __restrict__ w_s, const float* __restrict__ w_t,
    float* __restrict__ wT_s, float* __restrict__ wT_t)
{
  const float* w = blockIdx.y ? w_t : w_s;
  float* wT = blockIdx.y ? wT_t : wT_s;
  const int e = blockIdx.x * 256 + threadIdx.x;   // 0..73727
  const int co = e & 63;
  const int q = e >> 6;
  const int k9 = q % 9;
  const int ci = q / 9;
  wT[e] = w[(co * 128 + ci) * 9 + k9];
}

// ---------------------------------------------------------------------------
// conv0: 3x3 stride-2 pad-1, Cin=128 -> Cout=64, 64x64 -> 32x32.
// ---------------------------------------------------------------------------
__global__ __launch_bounds__(256) void conv0_kernel(
    const float* __restrict__ in_s, const float* __restrict__ wT_s, const float* __restrict__ b_s,
    float* __restrict__ outA_s, float* __restrict__ outB_s,
    const float* __restrict__ in_t, const float* __restrict__ wT_t, const float* __restrict__ b_t,
    float* __restrict__ outA_t, float* __restrict__ outB_t)
{
  const int tsel = blockIdx.y;
  const float* in   = tsel ? in_t  : in_s;
  const float* wT   = tsel ? wT_t  : wT_s;
  const float* bias = tsel ? b_t   : b_s;
  float* outA = tsel ? outA_t : outA_s;
  float* outB = tsel ? outB_t : outB_s;

  const int bx = blockIdx.x;
  const int b  = bx >> 4;
  const int y0 = (bx & 15) * 2;
  const int t  = threadIdx.x;
  const int x  = t & 31;
  const int cg = t >> 5;            // 0..7 -> co = cg*8..+7

  __shared__ float wch[4608];       // [cc][k9][co] = [8][9][64], flat
  __shared__ float inch[8][5][64];  // [ci_chunk][row][ix]

  float acc[2][8];
#pragma unroll
  for (int yy = 0; yy < 2; ++yy)
#pragma unroll
    for (int o = 0; o < 8; ++o) acc[yy][o] = 0.f;

  for (int ci0 = 0; ci0 < 128; ci0 += 8) {
    __syncthreads();
    {
      const float* wsrc = wT + ci0 * 576;
#pragma unroll 4
      for (int r = 0; r < 18; ++r) {
        const int e = t + 256 * r;
        wch[e] = wsrc[e];
      }
    }
#pragma unroll 2
    for (int r = 0; r < 10; ++r) {
      const int e = t + 256 * r;
      const int ix = e & 63;
      const int q = e >> 6;         // 0..39
      const int ry = q % 5;
      const int cc = q / 5;
      const int iy = 2 * y0 - 1 + ry;
      float v = 0.f;
      if (iy >= 0 && iy < 64) v = in[((b * 128 + ci0 + cc) * 64 + iy) * 64 + ix];
      inch[cc][ry][ix] = v;
    }
    __syncthreads();
#pragma unroll 1
    for (int cc = 0; cc < 8; ++cc) {
      float iv[5][3];
#pragma unroll
      for (int ry = 0; ry < 5; ++ry) {
#pragma unroll
        for (int kx = 0; kx < 3; ++kx) {
          const int ix = 2 * x + kx - 1;   // [-1, 63]
          iv[ry][kx] = (ix >= 0) ? inch[cc][ry][ix] : 0.f;
        }
      }
#pragma unroll
      for (int ky = 0; ky < 3; ++ky) {
#pragma unroll
        for (int kx = 0; kx < 3; ++kx) {
          const int k9 = ky * 3 + kx;
          const float4 wa = *reinterpret_cast<const float4*>(&wch[(cc * 9 + k9) * 64 + cg * 8]);
          const float4 wb = *reinterpret_cast<const float4*>(&wch[(cc * 9 + k9) * 64 + cg * 8 + 4]);
          const float wv[8] = {wa.x, wa.y, wa.z, wa.w, wb.x, wb.y, wb.z, wb.w};
          const float i0 = iv[ky][kx];
          const float i1 = iv[ky + 2][kx];
#pragma unroll
          for (int o = 0; o < 8; ++o) {
            acc[0][o] = fmaf(i0, wv[o], acc[0][o]);
            acc[1][o] = fmaf(i1, wv[o], acc[1][o]);
          }
        }
      }
    }
  }
#pragma unroll
  for (int o = 0; o < 8; ++o) {
    const int co = cg * 8 + o;
    const float bv = bias[co];
#pragma unroll
    for (int yy = 0; yy < 2; ++yy) {
      const int idx = (b * 64 + co) * 1024 + (y0 + yy) * 32 + x;
      const float val = acc[yy][o] + bv;
      outA[idx] = val;
      if (outB) outB[idx] = val;
    }
  }
}

// ---------------------------------------------------------------------------
// Generic out[g][64][1024] = W[g/wdiv][64][K] @ X[g][K][1024] + bias
// ---------------------------------------------------------------------------
__global__ __launch_bounds__(256) void gemm64_kernel(
    const float* __restrict__ W, int wstride, int wdiv,
    const float* __restrict__ X, int xstride,
    float* __restrict__ out, int ostride,
    float* __restrict__ out2, int o2stride,
    const float* __restrict__ bias, int bstride,
    int K)
{
  const int g  = blockIdx.x;
  const int n0 = blockIdx.y * 64;
  const float* Wg = W + (size_t)(g / wdiv) * wstride;
  const float* Xg = X + (size_t)g * xstride;
  const int t = threadIdx.x;
  __shared__ float Xs[32][64];
  __shared__ float Ws[32][64];
  const int tn = t & 15, cgp = t >> 4;
  const int n4 = tn * 4, co4 = cgp * 4;
  float acc[4][4] = {};

  for (int k0 = 0; k0 < K; k0 += 32) {
    {
      const int kk = t >> 4;
      const int nn = (t & 15) * 4;
      *reinterpret_cast<float4*>(&Xs[kk][nn]) =
          *reinterpret_cast<const float4*>(Xg + (size_t)(k0 + kk) * N_ + n0 + nn);
      *reinterpret_cast<float4*>(&Xs[kk + 16][nn]) =
          *reinterpret_cast<const float4*>(Xg + (size_t)(k0 + kk + 16) * N_ + n0 + nn);
    }
    {
      const int co = t & 63, q4 = t >> 6;
      const float* wp = Wg + (size_t)co * K + k0 + q4 * 8;
      const float4 a = *reinterpret_cast<const float4*>(wp);
      const float4 c = *reinterpret_cast<const float4*>(wp + 4);
      const int kb = q4 * 8;
      Ws[kb + 0][co] = a.x; Ws[kb + 1][co] = a.y; Ws[kb + 2][co] = a.z; Ws[kb + 3][co] = a.w;
      Ws[kb + 4][co] = c.x; Ws[kb + 5][co] = c.y; Ws[kb + 6][co] = c.z; Ws[kb + 7][co] = c.w;
    }
    __syncthreads();
#pragma unroll
    for (int kk = 0; kk < 32; ++kk) {
      const float4 xv = *reinterpret_cast<const float4*>(&Xs[kk][n4]);
      const float4 wv = *reinterpret_cast<const float4*>(&Ws[kk][co4]);
      const float xa[4] = {xv.x, xv.y, xv.z, xv.w};
      const float wa[4] = {wv.x, wv.y, wv.z, wv.w};
#pragma unroll
      for (int a = 0; a < 4; ++a)
#pragma unroll
        for (int b2 = 0; b2 < 4; ++b2)
          acc[a][b2] = fmaf(wa[a], xa[b2], acc[a][b2]);
    }
    __syncthreads();
  }

  float bv[4] = {0.f, 0.f, 0.f, 0.f};
  if (bias) {
    const float* bg = bias + (size_t)(g / wdiv) * bstride;
    bv[0] = bg[co4]; bv[1] = bg[co4 + 1]; bv[2] = bg[co4 + 2]; bv[3] = bg[co4 + 3];
  }
#pragma unroll
  for (int ii = 0; ii < 4; ++ii) {
    float4 o4;
    o4.x = acc[ii][0] + bv[ii]; o4.y = acc[ii][1] + bv[ii];
    o4.z = acc[ii][2] + bv[ii]; o4.w = acc[ii][3] + bv[ii];
    const int idx = (co4 + ii) * N_ + n0 + n4;
    *reinterpret_cast<float4*>(out + (size_t)g * ostride + idx) = o4;
    if (out2) {
      float* o2 = out2 + (size_t)g * o2stride + idx;
      o2[0] = o4.x; o2[1] = o4.y; o2[2] = o4.z; o2[3] = o4.w;
    }
  }
}

// ---------------------------------------------------------------------------
// kprep: k[g][64c][1024m] -> kT_hi/kT_lo[g][1024m][64c] (split bf16);
//        v[g] -> vbf[g] (bf16). grid (24, 4): per block 256-m chunk.
// ---------------------------------------------------------------------------
__global__ __launch_bounds__(256) void kprep_kernel(
    const float* __restrict__ kb, const float* __restrict__ vb,
    unsigned short* __restrict__ kTh, unsigned short* __restrict__ kTl,
    unsigned short* __restrict__ vbf)
{
  const int g = blockIdx.x;
  const int ch = blockIdx.y;
  const int t = threadIdx.x;
  const float* kg = kb + (size_t)g * PLANE;
  __shared__ float tl[64][65];

#pragma unroll 1
  for (int tile = 0; tile < 4; ++tile) {
    const int m0 = ch * 256 + tile * 64;
    __syncthreads();
#pragma unroll 4
    for (int r = 0; r < 16; ++r) {
      const int c = r * 4 + (t >> 6);
      tl[c][t & 63] = kg[c * N_ + m0 + (t & 63)];
    }
    __syncthreads();
    const int mm = t >> 2, cseg = (t & 3) * 16;
    uint32 hw[8], lw[8];
#pragma unroll
    for (int ii = 0; ii < 16; ++ii) {
      const float f = tl[cseg + ii][mm];
      const unsigned short h = f2bf(f);
      const unsigned short l = f2bf(f - bf2f(h));
      if (ii & 1) { hw[ii >> 1] |= (uint32)h << 16; lw[ii >> 1] |= (uint32)l << 16; }
      else        { hw[ii >> 1] = h;                lw[ii >> 1] = l; }
    }
    const size_t o = ((size_t)g * 1024 + m0 + mm) * 64 + cseg;
    uint4 h0; h0.x = hw[0]; h0.y = hw[1]; h0.z = hw[2]; h0.w = hw[3];
    uint4 h1; h1.x = hw[4]; h1.y = hw[5]; h1.z = hw[6]; h1.w = hw[7];
    uint4 l0; l0.x = lw[0]; l0.y = lw[1]; l0.z = lw[2]; l0.w = lw[3];
    uint4 l1; l1.x = lw[4]; l1.y = lw[5]; l1.z = lw[6]; l1.w = lw[7];
    *reinterpret_cast<uint4*>(kTh + o)     = h0;
    *reinterpret_cast<uint4*>(kTh + o + 8) = h1;
    *reinterpret_cast<uint4*>(kTl + o)     = l0;
    *reinterpret_cast<uint4*>(kTl + o + 8) = l1;
  }

  // v -> bf16 (8 elems/thread/iter, packed 16B stores)
  const float* vg = vb + (size_t)g * PLANE;
  unsigned short* vo = vbf + (size_t)g * PLANE;
  for (int e8 = ch * 2048 + t; e8 < (ch + 1) * 2048; e8 += 256) {
    const float4 a = *reinterpret_cast<const float4*>(vg + (size_t)e8 * 8);
    const float4 b = *reinterpret_cast<const float4*>(vg + (size_t)e8 * 8 + 4);
    uint4 u;
    u.x = pkbf(a.x, a.y); u.y = pkbf(a.z, a.w);
    u.z = pkbf(b.x, b.y); u.w = pkbf(b.z, b.w);
    *reinterpret_cast<uint4*>(vo + (size_t)e8 * 8) = u;
  }
}

// ---------------------------------------------------------------------------
// e_cam[i,j,b][c][d] = sum_n T[i,b,c,n] * S[j,b,d,n];  also atomic raw-sum.
// ---------------------------------------------------------------------------
__global__ __launch_bounds__(256) void ecam_kernel(
    const float* __restrict__ T, const float* __restrict__ S,
    float* __restrict__ ecam, float* __restrict__ esum_cam)
{
  const int bx = blockIdx.x;
  const int b = bx & 7;
  const int j = (bx >> 3) % 3;
  const int i = bx / 24;
  const float* Tg = T + (size_t)(i * 8 + b) * PLANE;
  const float* Sg = S + (size_t)(j * 8 + b) * PLANE;
  const int t = threadIdx.x;
  __shared__ float Ts[64 * 68];
  __shared__ float Ss[64 * 68];
  __shared__ float rs[4];
  float acc[4][4] = {};
  const int c0 = (t & 15) * 4, d0 = (t >> 4) * 4;

  for (int nb = 0; nb < 1024; nb += 64) {
    __syncthreads();
    {
      const int nn = t & 63, rb = t >> 6;
#pragma unroll
      for (int r = 0; r < 16; ++r) {
        const int row = rb * 16 + r;
        Ts[nn * 68 + row] = Tg[row * N_ + nb + nn];
        Ss[nn * 68 + row] = Sg[row * N_ + nb + nn];
      }
    }
    __syncthreads();
#pragma unroll 8
    for (int nn = 0; nn < 64; ++nn) {
      const float4 tv = *reinterpret_cast<const float4*>(&Ts[nn * 68 + c0]);
      const float4 sv = *reinterpret_cast<const float4*>(&Ss[nn * 68 + d0]);
      const float ta[4] = {tv.x, tv.y, tv.z, tv.w};
      const float sa[4] = {sv.x, sv.y, sv.z, sv.w};
#pragma unroll
      for (int ci = 0; ci < 4; ++ci)
#pragma unroll
        for (int di = 0; di < 4; ++di)
          acc[ci][di] = fmaf(ta[ci], sa[di], acc[ci][di]);
    }
  }
  float s = 0.f;
#pragma unroll
  for (int ci = 0; ci < 4; ++ci)
#pragma unroll
    for (int di = 0; di < 4; ++di) s += acc[ci][di];
  s = wred_sum(s);
  if ((t & 63) == 0) rs[t >> 6] = s;
  __syncthreads();
  if (t == 0) atomicAdd(esum_cam + i * 3 + j, rs[0] + rs[1] + rs[2] + rs[3]);

  float* eo = ecam + (size_t)((i * 3 + j) * 8 + b) * 4096;
#pragma unroll
  for (int ci = 0; ci < 4; ++ci) {
    float4 o4; o4.x = acc[ci][0]; o4.y = acc[ci][1]; o4.z = acc[ci][2]; o4.w = acc[ci][3];
    *reinterpret_cast<float4*>(eo + (c0 + ci) * 64 + d0) = o4;
  }
}

// ---------------------------------------------------------------------------
// attn_cam[i,b][c][d] = sum_j softmax_d(e_cam[i,j,b,c,:])[d]     grid 24
// ---------------------------------------------------------------------------
__global__ __launch_bounds__(256) void acam_kernel(
    const float* __restrict__ ecam, float* __restrict__ acam)
{
  const int bx = blockIdx.x;
  const int b = bx & 7, i = bx >> 3;
  const int t = threadIdx.x;
  const int c = t >> 2, seg = t & 3;
  float acc[16] = {};
#pragma unroll
  for (int j = 0; j < 3; ++j) {
    const float* e = ecam + (size_t)((i * 3 + j) * 8 + b) * 4096 + c * 64 + seg * 16;
    float ev[16];
#pragma unroll
    for (int r = 0; r < 4; ++r) {
      const float4 v4 = *reinterpret_cast<const float4*>(e + r * 4);
      ev[4 * r] = v4.x; ev[4 * r + 1] = v4.y; ev[4 * r + 2] = v4.z; ev[4 * r + 3] = v4.w;
    }
    float mx = ev[0];
#pragma unroll
    for (int r = 1; r < 16; ++r) mx = fmaxf(mx, ev[r]);
    mx = fmaxf(mx, __shfl_xor(mx, 1, 4));
    mx = fmaxf(mx, __shfl_xor(mx, 2, 4));
    float pv[16], ss = 0.f;
#pragma unroll
    for (int r = 0; r < 16; ++r) { pv[r] = __expf(ev[r] - mx); ss += pv[r]; }
    ss += __shfl_xor(ss, 1, 4);
    ss += __shfl_xor(ss, 2, 4);
    const float rc = 1.f / ss;
#pragma unroll
    for (int r = 0; r < 16; ++r) acc[r] += pv[r] * rc;
  }
  float* ao = acam + (size_t)(i * 8 + b) * 4096 + c * 64 + seg * 16;
#pragma unroll
  for (int r = 0; r < 4; ++r) {
    float4 o4; o4.x = acc[4 * r]; o4.y = acc[4 * r + 1]; o4.z = acc[4 * r + 2]; o4.w = acc[4 * r + 3];
    *reinterpret_cast<float4*>(ao + r * 4) = o4;
  }
}

// ---------------------------------------------------------------------------
// PAM via MFMA. grid 1536 = (i, b, 16-query tile), 4 waves.
// Swapped QK^T: D[m,n] = mfma(K^T frag, Q frag). Split-bf16 3-pass for logits.
// Per wave: 16 m-tiles (256 m) owned across all 3 j. pacc in regs; P -> LDS
// (bf16, XOR-swizzled) once; PV = mfma(V bf16, P^T).
// ---------------------------------------------------------------------------
__global__ __launch_bounds__(256, 2) void pam_mfma_kernel(
    const float* __restrict__ q, const unsigned short* __restrict__ kTh,
    const unsigned short* __restrict__ kTl, const unsigned short* __restrict__ vbf,
    const float* __restrict__ ocam, float* __restrict__ tgts, float* __restrict__ esum_pam)
{
  const int bx = blockIdx.x;
  const int qt = bx & 63;
  const int b  = (bx >> 6) & 7;
  const int i  = bx >> 9;
  const int n0 = qt * 16;
  const int t = threadIdx.x;
  const int lane = t & 63;
  const int wv = t >> 6;
  const int nl = lane & 15;          // n within tile (operand col / D col)
  const int g16 = lane >> 4;         // k-group

  __shared__ unsigned short Plds[16 * 1024];  // 32 KB, [n][m ^ (8n)]
  __shared__ float qlds[64 * 17];
  __shared__ float redmx[64];
  __shared__ float redse[64];
  __shared__ float redes[4];

  const size_t ibo = (size_t)(i * 8 + b) * PLANE;

  // stage q tile [64c][16n]
  const float* qg = q + ibo;
  for (int e = t; e < 1024; e += 256)
    qlds[(e >> 4) * 17 + (e & 15)] = qg[(e >> 4) * N_ + n0 + (e & 15)];
  __syncthreads();

  // Q B-fragments, split hi/lo: col n = nl, k(c) = ks*32 + g16*8 + idx
  short8 qhi[2], qlo[2];
#pragma unroll
  for (int ks = 0; ks < 2; ++ks) {
#pragma unroll
    for (int idx = 0; idx < 8; ++idx) {
      const float f = qlds[(ks * 32 + g16 * 8 + idx) * 17 + nl];
      const unsigned short h = f2bf(f);
      qhi[ks][idx] = (short)h;
      qlo[ks][idx] = (short)f2bf(f - bf2f(h));
    }
  }

  f32x4 pacc[16];
#pragma unroll
  for (int tt = 0; tt < 16; ++tt) pacc[tt] = f32x4{0.f, 0.f, 0.f, 0.f};

  const int wm0 = wv * 256;  // wave's m-range base

  for (int j = 0; j < 3; ++j) {
    __syncthreads();  // protect red* reuse across j
    const size_t ko = ((size_t)(j * 8 + b) * 1024 + wm0 + nl) * 64 + g16 * 8;
    const unsigned short* kh = kTh + ko;
    const unsigned short* kl = kTl + ko;

    f32x4 l4[16];
#pragma unroll
    for (int tt = 0; tt < 16; ++tt) {
      const int off = tt * 1024;  // 16 m-rows * 64 c
      const short8 kh0 = bcs8(*reinterpret_cast<const uint4*>(kh + off));
      const short8 kl0 = bcs8(*reinterpret_cast<const uint4*>(kl + off));
      const short8 kh1 = bcs8(*reinterpret_cast<const uint4*>(kh + off + 32));
      const short8 kl1 = bcs8(*reinterpret_cast<const uint4*>(kl + off + 32));
      f32x4 a = f32x4{0.f, 0.f, 0.f, 0.f};
      a = mfma16(kh0, qhi[0], a);
      a = mfma16(kh0, qlo[0], a);
      a = mfma16(kl0, qhi[0], a);
      a = mfma16(kh1, qhi[1], a);
      a = mfma16(kh1, qlo[1], a);
      a = mfma16(kl1, qhi[1], a);
      l4[tt] = a;
    }

    // stats: per-n max over this wave's 256 m (4-lane group), raw sum (wave)
    float pm = -3.4e38f, es = 0.f;
#pragma unroll
    for (int tt = 0; tt < 16; ++tt) {
#pragma unroll
      for (int r = 0; r < 4; ++r) { pm = fmaxf(pm, l4[tt][r]); es += l4[tt][r]; }
    }
    pm = fmaxf(pm, __shfl_xor(pm, 16, 64));
    pm = fmaxf(pm, __shfl_xor(pm, 32, 64));
    es = wred_sum(es);
    if (lane < 16) redmx[wv * 16 + lane] = pm;
    if (lane == 0) redes[wv] = es;
    __syncthreads();
    const float mx = fmaxf(fmaxf(redmx[nl], redmx[16 + nl]),
                           fmaxf(redmx[32 + nl], redmx[48 + nl]));
    if (t == 0) atomicAdd(esum_pam + i * 3 + j, redes[0] + redes[1] + redes[2] + redes[3]);

    float ps = 0.f;
#pragma unroll
    for (int tt = 0; tt < 16; ++tt) {
#pragma unroll
      for (int r = 0; r < 4; ++r) {
        l4[tt][r] = __expf(l4[tt][r] - mx);
        ps += l4[tt][r];
      }
    }
    ps += __shfl_xor(ps, 16, 64);
    ps += __shfl_xor(ps, 32, 64);
    if (lane < 16) redse[wv * 16 + lane] = ps;
    __syncthreads();
    const float rs = 1.f / (redse[nl] + redse[16 + nl] + redse[32 + nl] + redse[48 + nl]);
#pragma unroll
    for (int tt = 0; tt < 16; ++tt) {
#pragma unroll
      for (int r = 0; r < 4; ++r) pacc[tt][r] += l4[tt][r] * rs;
    }
  }

  // write P_sum -> Plds (bf16, swizzled: ushort idx = n*1024 + (m ^ 8n))
#pragma unroll
  for (int tt = 0; tt < 16; ++tt) {
    const int m = wm0 + tt * 16 + g16 * 4;
    uint2 w2;
    w2.x = pkbf(pacc[tt][0], pacc[tt][1]);
    w2.y = pkbf(pacc[tt][2], pacc[tt][3]);
    *reinterpret_cast<uint2*>(&Plds[nl * 1024 + (m ^ (nl * 8))]) = w2;
  }
  __syncthreads();

  // PV: D[c,n] = sum_m V[c,m] * P[n,m]; wave wv owns c-tile [16wv, 16wv+16)
  const unsigned short* vg = vbf + ibo + (size_t)(16 * wv + nl) * 1024 + g16 * 8;
  f32x4 oa = f32x4{0.f, 0.f, 0.f, 0.f};
  f32x4 ob = f32x4{0.f, 0.f, 0.f, 0.f};
#pragma unroll
  for (int ks = 0; ks < 32; ks += 2) {
    const int mb0 = ks * 32 + g16 * 8;
    const int mb1 = mb0 + 32;
    const short8 va0 = bcs8(*reinterpret_cast<const uint4*>(vg + ks * 32));
    const short8 pf0 = bcs8(*reinterpret_cast<const uint4*>(&Plds[nl * 1024 + (mb0 ^ (nl * 8))]));
    const short8 va1 = bcs8(*reinterpret_cast<const uint4*>(vg + ks * 32 + 32));
    const short8 pf1 = bcs8(*reinterpret_cast<const uint4*>(&Plds[nl * 1024 + (mb1 ^ (nl * 8))]));
    oa = mfma16(va0, pf0, oa);
    ob = mfma16(va1, pf1, ob);
  }
#pragma unroll
  for (int r = 0; r < 4; ++r) oa[r] += ob[r];

  // epilogue: fuse with out_cam, write tgts even slot
  const float* og = ocam + ibo;
  float* outg = tgts + (size_t)(2 * i * 8 + b) * PLANE;
#pragma unroll
  for (int r = 0; r < 4; ++r) {
    const int c = 16 * wv + g16 * 4 + r;
    const int idx = c * N_ + n0 + nl;
    outg[idx] = 0.5f * (oa[r] + og[idx]);
  }
}

// ---------------------------------------------------------------------------
// alpha[i][j] = 0.5*(softmax_j(mean e_pam) + softmax_j(mean e_cam))
// ---------------------------------------------------------------------------
__global__ void alpha_kernel(const float* __restrict__ esum, float* __restrict__ alpha)
{
  const int t = threadIdx.x;
  if (t >= 9) return;
  const int i = t / 3, j = t % 3;
  float p[3], c[3];
#pragma unroll
  for (int jj = 0; jj < 3; ++jj) {
    p[jj] = esum[i * 3 + jj] * (1.0f / 8388608.0f);
    c[jj] = esum[9 + i * 3 + jj] * (1.0f / 32768.0f);
  }
  const float mp = fmaxf(p[0], fmaxf(p[1], p[2]));
  const float mc = fmaxf(c[0], fmaxf(c[1], c[2]));
  float sp = 0.f, sc = 0.f;
#pragma unroll
  for (int jj = 0; jj < 3; ++jj) { sp += __expf(p[jj] - mp); sc += __expf(c[jj] - mc); }
  alpha[t] = 0.5f * (__expf(p[j] - mp) / sp + __expf(c[j] - mc) / sc);
}

// ---------------------------------------------------------------------------
extern "C" void kernel_launch(void* const* d_in, const int* in_sizes, int n_in,
                              void* d_out, int out_size, void* d_ws, size_t ws_size,
                              hipStream_t stream)
{
  const float* src0 = (const float*)d_in[0];
  const float* src1 = (const float*)d_in[1];
  const float* src2 = (const float*)d_in[2];
  const float* tgt0 = (const float*)d_in[3];
  const float* tgt1 = (const float*)d_in[4];
  const float* tgt2 = (const float*)d_in[5];
  const float* fs0_w = (const float*)d_in[6];  const float* fs0_b = (const float*)d_in[7];
  const float* fs1_w = (const float*)d_in[8];  const float* fs1_b = (const float*)d_in[9];
  const float* fs2_w = (const float*)d_in[10]; const float* fs2_b = (const float*)d_in[11];
  const float* ft0_w = (const float*)d_in[12]; const float* ft0_b = (const float*)d_in[13];
  const float* ft1_w = (const float*)d_in[14]; const float* ft1_b = (const float*)d_in[15];
  const float* ft2_w = (const float*)d_in[16]; const float* ft2_b = (const float*)d_in[17];
  const float* pq_w = (const float*)d_in[18];  const float* pq_b = (const float*)d_in[19];
  const float* pk_w = (const float*)d_in[20];  const float* pk_b = (const float*)d_in[21];
  const float* pv_w = (const float*)d_in[22];  const float* pv_b = (const float*)d_in[23];
  const float* cv_w = (const float*)d_in[24];  const float* cv_b = (const float*)d_in[25];

  float* out = (float*)d_out;
  float* S     = out;                 // srcs region doubles as S storage
  float* alpha = out + SZ;            // 9 floats
  float* tgts  = out + SZ + 9;        // [2L][B][PLANE]

  float* ws   = (float*)d_ws;
  float* T    = ws;
  float* qb   = ws + (size_t)SZ;
  float* kb   = ws + (size_t)2 * SZ;
  float* vb   = ws + (size_t)3 * SZ;
  float* vcb  = ws + (size_t)4 * SZ;
  float* ocam = ws + (size_t)5 * SZ;
  float* ecam = ws + (size_t)6 * SZ;                 // 294912
  float* acam = ws + (size_t)6 * SZ + 294912;        // 98304
  float* esum = ws + (size_t)6 * SZ + 393216;        // 18 (pam 9, cam 9)

  // bf16 buffers appended after the fp32 region
  unsigned short* kTh = (unsigned short*)(ws + (size_t)6 * SZ + 393216 + 256);
  unsigned short* kTl = kTh + (size_t)24 * PLANE;
  unsigned short* vbf = kTl + (size_t)24 * PLANE;

  // Transposed conv0 weights live temporarily in qb (overwritten later by q proj)
  float* wTs = qb;
  float* wTt = qb + 73728;

  hipMemsetAsync(esum, 0, 18 * sizeof(float), stream);

  // Pre-transpose the 3x3 weights for coalesced, math-free LDS staging
  wtrans_kernel<<<dim3(288, 2), 256, 0, stream>>>(fs0_w, ft0_w, wTs, wTt);

  // Fit convs (S goes straight into d_out; T dual-written into tgts odd slots)
  conv0_kernel<<<dim3(128, 2), 256, 0, stream>>>(
      src0, wTs, fs0_b, S, nullptr,
      tgt0, wTt, ft0_b, T, tgts + (size_t)1 * BPL);
  gemm64_kernel<<<dim3(8, 16), 256, 0, stream>>>(fs1_w, 0, 1, src1, 256 * N_, S + BPL, PLANE,
                                                 nullptr, 0, fs1_b, 0, 256);
  gemm64_kernel<<<dim3(8, 16), 256, 0, stream>>>(fs2_w, 0, 1, src2, 512 * N_, S + 2 * BPL, PLANE,
                                                 nullptr, 0, fs2_b, 0, 512);
  gemm64_kernel<<<dim3(8, 16), 256, 0, stream>>>(ft1_w, 0, 1, tgt1, 256 * N_, T + BPL, PLANE,
                                                 tgts + (size_t)3 * BPL, PLANE, ft1_b, 0, 256);
  gemm64_kernel<<<dim3(8, 16), 256, 0, stream>>>(ft2_w, 0, 1, tgt2, 512 * N_, T + 2 * BPL, PLANE,
                                                 tgts + (size_t)5 * BPL, PLANE, ft2_b, 0, 512);

  // Projections q,k,v,vc
  gemm64_kernel<<<dim3(24, 16), 256, 0, stream>>>(pq_w, 4096, 8, T, PLANE, qb, PLANE,
                                                  nullptr, 0, pq_b, 64, 64);
  gemm64_kernel<<<dim3(24, 16), 256, 0, stream>>>(pk_w, 4096, 8, S, PLANE, kb, PLANE,
                                                  nullptr, 0, pk_b, 64, 64);
  gemm64_kernel<<<dim3(24, 16), 256, 0, stream>>>(pv_w, 4096, 8, T, PLANE, vb, PLANE,
                                                  nullptr, 0, pv_b, 64, 64);
  gemm64_kernel<<<dim3(24, 16), 256, 0, stream>>>(cv_w, 4096, 8, T, PLANE, vcb, PLANE,
                                                  nullptr, 0, cv_b, 64, 64);

  // Pack k (transposed, split-bf16) and v (bf16) for the MFMA attention
  kprep_kernel<<<dim3(24, 4), 256, 0, stream>>>(kb, vb, kTh, kTl, vbf);

  // CAM
  ecam_kernel<<<72, 256, 0, stream>>>(T, S, ecam, esum + 9);
  acam_kernel<<<24, 256, 0, stream>>>(ecam, acam);
  gemm64_kernel<<<dim3(24, 16), 256, 0, stream>>>(acam, 4096, 1, vcb, PLANE, ocam, PLANE,
                                                  nullptr, 0, nullptr, 0, 64);

  // PAM + fuse (writes tgts even slots = 0.5*(out_pam + out_cam))
  pam_mfma_kernel<<<1536, 256, 0, stream>>>(qb, kTh, kTl, vbf, ocam, tgts, esum);

  alpha_kernel<<<1, 64, 0, stream>>>(esum, alpha);
}